// Round 1
// baseline (593.213 us; speedup 1.0000x reference)
//
#include <hip/hip_runtime.h>
#include <float.h>

#define B_ 4
#define C_ 64
#define N_ 4096
#define O_ 64
#define K_ 20
#define EPS_ 1e-5f

// ws layout (in floats)
#define OFF_XX   ((size_t)0)              // 16384
#define OFF_A    ((size_t)16384)          // 1048576
#define OFF_CC   ((size_t)1064960)        // 1048576
#define OFF_YMAX ((size_t)2113536)        // 1048576
#define OFF_YMIN ((size_t)3162112)        // 1048576
#define OFF_SUMS ((size_t)4210688)        // 256: sum1, sumsq1, sum2, sumsq2
#define OFF_ST   ((size_t)4210944)        // 256: S1, T1, S2, T2
#define OFF_IDX  ((size_t)4211200)        // 327680 ints

// ---------------- K0: squared norms xx[b][n] ----------------
__global__ __launch_bounds__(256) void k_xx(const float* __restrict__ x,
                                            float* __restrict__ xx) {
  int t = blockIdx.x * 256 + threadIdx.x;     // 0 .. 16383
  int b = t >> 12, n = t & 4095;
  const float* xp = x + (size_t)b * C_ * N_ + n;
  float acc = 0.f;
#pragma unroll
  for (int c = 0; c < 64; ++c) {
    float v = xp[c * N_];
    acc = fmaf(v, v, acc);
  }
  xx[t] = acc;
}

// ---------------- K1: kNN top-20 (smallest dist, tie -> smaller j) --------
// grid 4096 blocks: block = (b, i0=4 rows). 256 threads = 4 waves.
__global__ __launch_bounds__(256, 2) void k_knn(const float* __restrict__ x,
                                                const float* __restrict__ xx,
                                                int* __restrict__ idxout) {
  __shared__ float lds[16384];   // 64 KB: xi staging (first 256) then 4x4096 dists
  const int tid = threadIdx.x;
  const int bid = blockIdx.x;
  const int b = bid >> 10;
  const int i0 = (bid & 1023) << 2;
  const float* xb = x + (size_t)b * C_ * N_;

  {  // stage x_i for 4 rows: lds[r*64+c]
    int r = tid >> 6, c = tid & 63;
    lds[r * 64 + c] = xb[c * N_ + i0 + r];
  }
  __syncthreads();

  float xxi[4];
#pragma unroll
  for (int r = 0; r < 4; ++r) xxi[r] = xx[b * N_ + i0 + r];

  float d[4][16];  // [row][g*4+l]
#pragma unroll
  for (int g = 0; g < 4; ++g) {
    const int jbase = (g * 256 + tid) * 4;
    float acc[4][4];
#pragma unroll
    for (int r = 0; r < 4; ++r)
#pragma unroll
      for (int l = 0; l < 4; ++l) acc[r][l] = 0.f;
#pragma unroll 8
    for (int c = 0; c < 64; ++c) {
      float4 xv = *(const float4*)(xb + c * N_ + jbase);
#pragma unroll
      for (int r = 0; r < 4; ++r) {
        float xi = lds[r * 64 + c];
        acc[r][0] = fmaf(xi, xv.x, acc[r][0]);
        acc[r][1] = fmaf(xi, xv.y, acc[r][1]);
        acc[r][2] = fmaf(xi, xv.z, acc[r][2]);
        acc[r][3] = fmaf(xi, xv.w, acc[r][3]);
      }
    }
    float4 xxj = *(const float4*)(xx + b * N_ + jbase);
#pragma unroll
    for (int r = 0; r < 4; ++r) {
      d[r][g * 4 + 0] = (xxi[r] - 2.f * acc[r][0]) + xxj.x;
      d[r][g * 4 + 1] = (xxi[r] - 2.f * acc[r][1]) + xxj.y;
      d[r][g * 4 + 2] = (xxi[r] - 2.f * acc[r][2]) + xxj.z;
      d[r][g * 4 + 3] = (xxi[r] - 2.f * acc[r][3]) + xxj.w;
    }
  }
  __syncthreads();  // xi region about to be overwritten

  // dump all 4 rows of dists to LDS
#pragma unroll
  for (int r = 0; r < 4; ++r) {
#pragma unroll
    for (int g = 0; g < 4; ++g) {
      float4 v = make_float4(d[r][g * 4 + 0], d[r][g * 4 + 1],
                             d[r][g * 4 + 2], d[r][g * 4 + 3]);
      *(float4*)(&lds[r * 4096 + (g * 256 + tid) * 4]) = v;
    }
  }
  __syncthreads();

  // selection: wave w owns row w. Per-lane sorted top-4 cache over its 64
  // values (j = i*64+lane), 20 rounds of wave argmin, pop+mark+rare refill.
  const int w = tid >> 6, lane = tid & 63;
  float* rowd = &lds[w * 4096];

  float c0 = FLT_MAX, c1 = FLT_MAX, c2 = FLT_MAX, c3 = FLT_MAX;
  int j0_ = 0x7fffffff, j1_ = 0x7fffffff, j2_ = 0x7fffffff, j3_ = 0x7fffffff;

  auto ins = [&](float v, int j) {
    if (v < c3) {   // scan order is j-ascending -> stable == lexicographic
      c3 = v; j3_ = j;
      if (c3 < c2) { float tv = c2; c2 = c3; c3 = tv; int tj = j2_; j2_ = j3_; j3_ = tj; }
      if (c2 < c1) { float tv = c1; c1 = c2; c2 = tv; int tj = j1_; j1_ = j2_; j2_ = tj; }
      if (c1 < c0) { float tv = c0; c0 = c1; c1 = tv; int tj = j0_; j0_ = j1_; j1_ = tj; }
    }
  };

#pragma unroll 4
  for (int i = 0; i < 64; ++i) {
    float v = rowd[i * 64 + lane];
    ins(v, i * 64 + lane);
  }

  int* myidx = idxout + ((size_t)(b * N_) + i0 + w) * K_;
  for (int t = 0; t < K_; ++t) {
    float v = c0; int jv = j0_;
#pragma unroll
    for (int m = 1; m < 64; m <<= 1) {
      float ov = __shfl_xor(v, m, 64);
      int oj = __shfl_xor(jv, m, 64);
      if (ov < v || (ov == v && oj < jv)) { v = ov; jv = oj; }
    }
    if (lane == 0) myidx[t] = jv;
    if (jv == j0_) {           // unique owner (j unique; sentinel can't win)
      rowd[jv] = FLT_MAX;      // mark in own partition (same-lane RAW only)
      c0 = c1; j0_ = j1_; c1 = c2; j1_ = j2_; c2 = c3; j2_ = j3_;
      c3 = FLT_MAX; j3_ = 0x7fffffff;
      if (c0 == FLT_MAX) {     // cache drained -> refill (rare)
        for (int i = 0; i < 64; ++i) {
          float v2 = rowd[i * 64 + lane];
          ins(v2, i * 64 + lane);
        }
      }
    }
  }
}

// ---------------- K2: A = w1a.x, Cc = (w1b-w1a).x, layout [b][n][o] -------
__global__ __launch_bounds__(256) void k_aw(const float* __restrict__ x,
                                            const float* __restrict__ w1,
                                            float* __restrict__ A,
                                            float* __restrict__ Cc) {
  int t = blockIdx.x * 256 + threadIdx.x;  // = p*64 + o
  int o = t & 63;
  int p = t >> 6;
  int n = p & 4095, b = p >> 12;
  const float* xp = x + (size_t)b * C_ * N_ + n;
  const float* wp = w1 + o * 128;
  float a = 0.f, cc = 0.f;
#pragma unroll 8
  for (int c = 0; c < 64; ++c) {
    float xv = xp[c * N_];
    float wA = wp[c], wB = wp[64 + c];
    a = fmaf(xv, wA, a);
    cc = fmaf(xv, wB - wA, cc);
  }
  A[t] = a;
  Cc[t] = cc;
}

// ---------------- K3: BN1 stats (sum, sumsq per channel over all edges) ---
__global__ __launch_bounds__(256) void k_stats1(const float* __restrict__ A,
                                                const float* __restrict__ Cc,
                                                const int* __restrict__ idx,
                                                const float* __restrict__ b1,
                                                float* __restrict__ sums) {
  int tid = threadIdx.x;
  int c = tid & 63, q = tid >> 6;
  float b1c = b1[c];
  float s = 0.f, ss = 0.f;
  int ebase = blockIdx.x * 1024 + q;
  for (int it = 0; it < 256; ++it) {
    int e = ebase + it * 4;                 // < 327680
    int b = e / 81920;
    int r1 = e - b * 81920;
    int ip = r1 / 20;
    int kk = r1 - ip * 20;
    int p = (b << 12) + ip;
    int j = idx[p * 20 + kk];
    float v = A[((b << 12) + j) * 64 + c] + Cc[p * 64 + c] + b1c;
    s += v;
    ss = fmaf(v, v, ss);
  }
  __shared__ float red[8][64];
  red[q][c] = s;
  red[4 + q][c] = ss;
  __syncthreads();
  if (q == 0) {
    float S = red[0][c] + red[1][c] + red[2][c] + red[3][c];
    float SS = red[4][c] + red[5][c] + red[6][c] + red[7][c];
    atomicAdd(&sums[c], S);
    atomicAdd(&sums[64 + c], SS);
  }
}

// ---------------- K4: finalize BN1 -> S1, T1 ----------------
__global__ void k_fin1(const float* __restrict__ sums, const float* __restrict__ b1,
                       const float* __restrict__ g1, const float* __restrict__ be1,
                       float* __restrict__ ST) {
  int o = threadIdx.x;
  const float E = 327680.f;
  float m = sums[o] / E;
  float var = fmaxf(sums[64 + o] / E - m * m, 0.f);
  float s = g1[o] / sqrtf(var + EPS_);
  ST[o] = s;
  ST[64 + o] = be1[o] + (b1[o] - m) * s;   // h = relu((A+Cc)*S1 + T1)
}

// ---------------- K5: layer-2 matvec + BN2 stats + per-point max/min ------
__global__ __launch_bounds__(256, 2) void k_layer2(
    const float* __restrict__ A, const float* __restrict__ Cc,
    const int* __restrict__ idx, const float* __restrict__ ST1,
    const float* __restrict__ w2, const float* __restrict__ b2,
    float* __restrict__ ymax, float* __restrict__ ymin,
    float* __restrict__ sums2) {
  const int tid = threadIdx.x;
  const int lane = tid & 63, w = tid >> 6;
  float w2r[64];
#pragma unroll
  for (int c = 0; c < 64; ++c) w2r[c] = w2[lane * 64 + c];
  const float S1l = ST1[lane], T1l = ST1[64 + lane], b2l = b2[lane];
  float psum = 0.f, pss = 0.f;
  for (int it = 0; it < 8; ++it) {
    int p = blockIdx.x * 32 + w * 8 + it;   // wave-uniform point id
    int b = p >> 12;
    float cc = Cc[p * 64 + lane];
    float mx = -FLT_MAX, mn = FLT_MAX;
    for (int kk = 0; kk < 20; ++kk) {
      int j = idx[p * 20 + kk];
      float a = A[((b << 12) + j) * 64 + lane];
      float h = fmaxf(0.f, fmaf(a + cc, S1l, T1l));  // lane holds h[c=lane]
      int hb = __float_as_int(h);
      float y = b2l;
#pragma unroll
      for (int c = 0; c < 64; ++c) {
        float hc = __int_as_float(__builtin_amdgcn_readlane(hb, c));
        y = fmaf(w2r[c], hc, y);
      }
      mx = fmaxf(mx, y);
      mn = fminf(mn, y);
      psum += y;
      pss = fmaf(y, y, pss);
    }
    ymax[p * 64 + lane] = mx;
    ymin[p * 64 + lane] = mn;
  }
  __shared__ float red2[8][64];
  red2[w][lane] = psum;
  red2[4 + w][lane] = pss;
  __syncthreads();
  if (w == 0) {
    float S = red2[0][lane] + red2[1][lane] + red2[2][lane] + red2[3][lane];
    float SS = red2[4][lane] + red2[5][lane] + red2[6][lane] + red2[7][lane];
    atomicAdd(&sums2[lane], S);
    atomicAdd(&sums2[64 + lane], SS);
  }
}

// ---------------- K6a: finalize BN2 -> S2, T2 ----------------
__global__ void k_fin2(const float* __restrict__ sums2, const float* __restrict__ g2,
                       const float* __restrict__ be2, float* __restrict__ ST2) {
  int o = threadIdx.x;
  const float E = 327680.f;
  float m = sums2[o] / E;
  float var = fmaxf(sums2[64 + o] / E - m * m, 0.f);
  float s = g2[o] / sqrtf(var + EPS_);
  ST2[o] = s;
  ST2[64 + o] = be2[o] - m * s;  // b2 already inside y2
}

// ---------------- K6b: epilogue out[b][o][n] ----------------
__global__ __launch_bounds__(256) void k_out(const float* __restrict__ ymax,
                                             const float* __restrict__ ymin,
                                             const float* __restrict__ ST2,
                                             float* __restrict__ out) {
  int t = blockIdx.x * 256 + threadIdx.x;  // = ((b*64)+o)*4096 + n
  int n = t & 4095;
  int o = (t >> 12) & 63;
  int b = t >> 18;
  float s = ST2[o], tt = ST2[64 + o];
  int p = (b << 12) + n;
  // max over k commutes with monotone-increasing affine+relu; if s<0 use min
  float v = (s >= 0.f) ? ymax[p * 64 + o] : ymin[p * 64 + o];
  out[t] = fmaxf(0.f, fmaf(v, s, tt));
}

extern "C" void kernel_launch(void* const* d_in, const int* in_sizes, int n_in,
                              void* d_out, int out_size, void* d_ws, size_t ws_size,
                              hipStream_t stream) {
  const float* x   = (const float*)d_in[0];
  const float* w1  = (const float*)d_in[1];
  const float* b1  = (const float*)d_in[2];
  const float* g1  = (const float*)d_in[3];
  const float* be1 = (const float*)d_in[4];
  const float* w2  = (const float*)d_in[5];
  const float* b2  = (const float*)d_in[6];
  const float* g2  = (const float*)d_in[7];
  const float* be2 = (const float*)d_in[8];
  float* out = (float*)d_out;
  float* ws = (float*)d_ws;

  float* xx   = ws + OFF_XX;
  float* A    = ws + OFF_A;
  float* Cc   = ws + OFF_CC;
  float* ymax = ws + OFF_YMAX;
  float* ymin = ws + OFF_YMIN;
  float* sums = ws + OFF_SUMS;   // [sum1 | sumsq1 | sum2 | sumsq2]
  float* ST1  = ws + OFF_ST;     // [S1 | T1 | S2 | T2]
  float* ST2  = ST1 + 128;
  int*   idx  = (int*)(ws + OFF_IDX);

  hipMemsetAsync(sums, 0, 256 * sizeof(float), stream);

  k_xx    <<<64,   256, 0, stream>>>(x, xx);
  k_knn   <<<4096, 256, 0, stream>>>(x, xx, idx);
  k_aw    <<<4096, 256, 0, stream>>>(x, w1, A, Cc);
  k_stats1<<<320,  256, 0, stream>>>(A, Cc, idx, b1, sums);
  k_fin1  <<<1,    64,  0, stream>>>(sums, b1, g1, be1, ST1);
  k_layer2<<<512,  256, 0, stream>>>(A, Cc, idx, ST1, w2, b2, ymax, ymin, sums + 128);
  k_fin2  <<<1,    64,  0, stream>>>(sums + 128, g2, be2, ST2);
  k_out   <<<4096, 256, 0, stream>>>(ymax, ymin, ST2, out);
}

// Round 2
// 454.073 us; speedup vs baseline: 1.3064x; 1.3064x over previous
//
#include <hip/hip_runtime.h>
#include <float.h>

#define B_ 4
#define C_ 64
#define N_ 4096
#define O_ 64
#define K_ 20
#define EPS_ 1e-5f

typedef float f32x4 __attribute__((ext_vector_type(4)));
typedef short s16x8 __attribute__((ext_vector_type(8)));

union Frag { uint4 u; s16x8 s; };

// ws layout (in float slots)
#define OFF_XX   ((size_t)0)              // 16384
#define OFF_A    ((size_t)16384)          // 1048576
#define OFF_CC   ((size_t)1064960)        // 1048576
#define OFF_YMAX ((size_t)2113536)        // 1048576  (xt lives here until k_layer2)
#define OFF_YMIN ((size_t)3162112)        // 1048576  (Phi+Plo live here until k_layer2)
#define OFF_SUMS ((size_t)4210688)        // 256
#define OFF_ST   ((size_t)4210944)        // 256
#define OFF_IDX  ((size_t)4211200)        // 327680 ints
// aliases (dead after k_knn2, before k_layer2 writes ymax/ymin):
#define OFF_XT   OFF_YMAX                 // 1048576 floats
#define OFF_PHI  OFF_YMIN                 // 524288 float-slots = 1048576 bf16
#define OFF_PLO  (OFF_YMIN + 524288)      // 524288 float-slots

__device__ inline ushort f2bf(float f) {
  uint u = __float_as_uint(f);
  return (ushort)((u + 0x7fffu + ((u >> 16) & 1u)) >> 16);
}
__device__ inline float bf2f(ushort h) { return __uint_as_float(((uint)h) << 16); }

// ---------------- K0: squared norms xx[b][n] (exact fp32) ----------------
__global__ __launch_bounds__(256) void k_xx(const float* __restrict__ x,
                                            float* __restrict__ xx) {
  int t = blockIdx.x * 256 + threadIdx.x;
  int b = t >> 12, n = t & 4095;
  const float* xp = x + (size_t)b * C_ * N_ + n;
  float acc = 0.f;
#pragma unroll
  for (int c = 0; c < 64; ++c) {
    float v = xp[c * N_];
    acc = fmaf(v, v, acc);
  }
  xx[t] = acc;
}

// ---------------- K0b: transpose xt[b][n][c] = x[b][c][n] ----------------
__global__ __launch_bounds__(256) void k_xt(const float* __restrict__ x,
                                            float* __restrict__ xt) {
  int t = blockIdx.x * 256 + threadIdx.x;   // wave = one point p, lanes = c
  int c = t & 63;
  int p = t >> 6;
  int b = p >> 12, n = p & 4095;
  xt[(size_t)p * 64 + c] = x[((size_t)b * 64 + c) * N_ + n];
}

// ---------------- K0c: pack bf16 hi/lo in MFMA fragment order -------------
// frag group g = ((b*256 + ntile)*2 + ktile); lane holds point n=ntile*16+(lane&15),
// k = ktile*32 + (lane>>4)*8 + e  (A-row and B-col layouts coincide).
__global__ __launch_bounds__(256) void k_pack(const float* __restrict__ x,
                                              ushort* __restrict__ Phi,
                                              ushort* __restrict__ Plo) {
  int t = blockIdx.x * 256 + threadIdx.x;   // 131072 threads
  int lane = t & 63;
  int g = t >> 6;                           // 0..2047
  int kt = g & 1, nt = (g >> 1) & 255, b = g >> 9;
  int n = nt * 16 + (lane & 15);
  int cbase = kt * 32 + ((lane >> 4) << 3);
  ushort hi[8], lo[8];
#pragma unroll
  for (int e = 0; e < 8; ++e) {
    float v = x[((size_t)b * 64 + cbase + e) * N_ + n];
    ushort h = f2bf(v);
    float l = v - bf2f(h);
    hi[e] = h;
    lo[e] = f2bf(l);
  }
  size_t base = (size_t)g * 512 + lane * 8;
  uint4 uh, ul;
  uh.x = hi[0] | ((uint)hi[1] << 16); uh.y = hi[2] | ((uint)hi[3] << 16);
  uh.z = hi[4] | ((uint)hi[5] << 16); uh.w = hi[6] | ((uint)hi[7] << 16);
  ul.x = lo[0] | ((uint)lo[1] << 16); ul.y = lo[2] | ((uint)lo[3] << 16);
  ul.z = lo[4] | ((uint)lo[5] << 16); ul.w = lo[6] | ((uint)lo[7] << 16);
  *(uint4*)(Phi + base) = uh;
  *(uint4*)(Plo + base) = ul;
}

// ---------------- K1: kNN via MFMA + histogram threshold + exact refine ---
// 512 blocks: (b, i-tile of 32 rows). 256 thr = 4 waves.
__global__ __launch_bounds__(256, 2) void k_knn2(
    const ushort* __restrict__ Phi, const ushort* __restrict__ Plo,
    const float* __restrict__ xx, const float* __restrict__ xt,
    int* __restrict__ idxout) {
  __shared__ uint  hist[32 * 257];   // 32.9 KB
  __shared__ float xi[32 * 64];      // 8 KB
  __shared__ float xxi[32];
  __shared__ float Tsh[32];
  __shared__ uint  cnt[32];
  __shared__ int   cand[32 * 64];    // 8 KB

  const int tid = threadIdx.x;
  const int lane = tid & 63, w = tid >> 6;
  const int b = blockIdx.x >> 7;
  const int i0 = (blockIdx.x & 127) << 5;
  const int bN = b << 12;

  for (int i = tid; i < 32 * 257; i += 256) hist[i] = 0;
  if (tid < 32) { xxi[tid] = xx[bN + i0 + tid]; cnt[tid] = 0; }
  {
    int f0 = tid * 8;
    const float* src = xt + ((size_t)bN + i0 + (f0 >> 6)) * 64 + (f0 & 63);
#pragma unroll
    for (int e = 0; e < 8; ++e) xi[f0 + e] = src[e];
  }
  __syncthreads();

  // A fragments for both 16-row subtiles, both k-tiles, hi and lo
  Frag ahi[2][2], alo[2][2];
#pragma unroll
  for (int isub = 0; isub < 2; ++isub) {
    int nt = (i0 >> 4) + isub;
#pragma unroll
    for (int kt = 0; kt < 2; ++kt) {
      size_t off = ((size_t)((b * 256 + nt) * 2 + kt)) * 512 + lane * 8;
      ahi[isub][kt].u = *(const uint4*)(Phi + off);
      alo[isub][kt].u = *(const uint4*)(Plo + off);
    }
  }
  float xxr[8];
#pragma unroll
  for (int isub = 0; isub < 2; ++isub)
#pragma unroll
    for (int r = 0; r < 4; ++r)
      xxr[isub * 4 + r] = xxi[isub * 16 + ((lane >> 4) << 2) + r];

  for (int pass = 0; pass < 2; ++pass) {
    for (int js = w; js < 256; js += 4) {
      const int j0 = js * 16;
      Frag bhi[2], blo[2];
#pragma unroll
      for (int kt = 0; kt < 2; ++kt) {
        size_t off = ((size_t)((b * 256 + js) * 2 + kt)) * 512 + lane * 8;
        bhi[kt].u = *(const uint4*)(Phi + off);
        blo[kt].u = *(const uint4*)(Plo + off);
      }
      const float xxj = xx[bN + j0 + (lane & 15)];
      const int jme = j0 + (lane & 15);
#pragma unroll
      for (int isub = 0; isub < 2; ++isub) {
        f32x4 acc = {0.f, 0.f, 0.f, 0.f};
        acc = __builtin_amdgcn_mfma_f32_16x16x32_bf16(ahi[isub][0].s, bhi[0].s, acc, 0, 0, 0);
        acc = __builtin_amdgcn_mfma_f32_16x16x32_bf16(ahi[isub][1].s, bhi[1].s, acc, 0, 0, 0);
        acc = __builtin_amdgcn_mfma_f32_16x16x32_bf16(ahi[isub][0].s, blo[0].s, acc, 0, 0, 0);
        acc = __builtin_amdgcn_mfma_f32_16x16x32_bf16(ahi[isub][1].s, blo[1].s, acc, 0, 0, 0);
        acc = __builtin_amdgcn_mfma_f32_16x16x32_bf16(alo[isub][0].s, bhi[0].s, acc, 0, 0, 0);
        acc = __builtin_amdgcn_mfma_f32_16x16x32_bf16(alo[isub][1].s, bhi[1].s, acc, 0, 0, 0);
#pragma unroll
        for (int r = 0; r < 4; ++r) {
          int rowl = isub * 16 + ((lane >> 4) << 2) + r;
          float d = fmaf(-2.f, acc[r], xxr[isub * 4 + r]) + xxj;
          if (pass == 0) {
            int bk = (int)d;
            bk = bk < 0 ? 0 : (bk > 255 ? 255 : bk);
            atomicAdd(&hist[rowl * 257 + bk], 1u);
          } else {
            if (d <= Tsh[rowl]) {
              uint pos = atomicAdd(&cnt[rowl], 1u);
              if (pos < 64) cand[rowl * 64 + pos] = jme;
            }
          }
        }
      }
    }
    __syncthreads();
    if (pass == 0) {
      if (tid < 32) {
        uint cum = 0;
        int tb = 255;
        for (int k = 0; k < 256; ++k) {
          cum += hist[tid * 257 + k];
          if (cum >= 20u && tb == 255) tb = k;
        }
        Tsh[tid] = (float)(tb + 1) + 0.25f;
      }
      __syncthreads();
    }
  }

  // exact refine + bitonic top-20 (one row per wave iteration)
  for (int rr = 0; rr < 8; ++rr) {
    const int row = w * 8 + rr;
    const int nc = (int)min(cnt[row], 64u);
    unsigned long long key = ~0ULL;
    if (lane < nc) {
      int j = cand[row * 64 + lane];
      const float* xj = xt + ((size_t)bN + j) * 64;
      const float* xic = &xi[row * 64];
      float dot = 0.f;
#pragma unroll 8
      for (int c = 0; c < 64; ++c) dot = fmaf(xic[c], xj[c], dot);
      float dex = (xxi[row] - 2.f * dot) + xx[bN + j];
      uint fb = __float_as_uint(dex);
      fb = (fb & 0x80000000u) ? ~fb : (fb | 0x80000000u);  // order-preserving
      key = (((unsigned long long)fb) << 32) | (uint)j;
    }
#pragma unroll
    for (int k2 = 2; k2 <= 64; k2 <<= 1) {
#pragma unroll
      for (int mm = k2 >> 1; mm >= 1; mm >>= 1) {
        uint klo = (uint)key, khi = (uint)(key >> 32);
        uint olo = __shfl_xor((int)klo, mm, 64);
        uint ohi = __shfl_xor((int)khi, mm, 64);
        unsigned long long o = (((unsigned long long)ohi) << 32) | olo;
        bool up = ((lane & k2) == 0);
        bool lowhalf = ((lane & mm) == 0);
        bool keepmin = (up == lowhalf);
        key = keepmin ? (key < o ? key : o) : (key > o ? key : o);
      }
    }
    if (lane < 20) idxout[((size_t)bN + i0 + row) * 20 + lane] = (int)(uint)key;
  }
}

// ---------------- K2: A = w1a.x, Cc = (w1b-w1a).x, layout [b][n][o] -------
__global__ __launch_bounds__(256) void k_aw(const float* __restrict__ x,
                                            const float* __restrict__ w1,
                                            float* __restrict__ A,
                                            float* __restrict__ Cc) {
  int t = blockIdx.x * 256 + threadIdx.x;
  int o = t & 63;
  int p = t >> 6;
  int n = p & 4095, b = p >> 12;
  const float* xp = x + (size_t)b * C_ * N_ + n;
  const float* wp = w1 + o * 128;
  float a = 0.f, cc = 0.f;
#pragma unroll 8
  for (int c = 0; c < 64; ++c) {
    float xv = xp[c * N_];
    float wA = wp[c], wB = wp[64 + c];
    a = fmaf(xv, wA, a);
    cc = fmaf(xv, wB - wA, cc);
  }
  A[t] = a;
  Cc[t] = cc;
}

// ---------------- K3: BN1 stats ----------------
__global__ __launch_bounds__(256) void k_stats1(const float* __restrict__ A,
                                                const float* __restrict__ Cc,
                                                const int* __restrict__ idx,
                                                const float* __restrict__ b1,
                                                float* __restrict__ sums) {
  int tid = threadIdx.x;
  int c = tid & 63, q = tid >> 6;
  float b1c = b1[c];
  float s = 0.f, ss = 0.f;
  int ebase = blockIdx.x * 128 + q * 32;
  for (int it = 0; it < 32; ++it) {
    int e = ebase + it;                    // < 327680; e = pl*20 + kk
    int pl = e / 20;
    int b = pl >> 12;
    int j = idx[e];
    float v = A[(((size_t)b << 12) + j) * 64 + c] + Cc[(size_t)pl * 64 + c] + b1c;
    s += v;
    ss = fmaf(v, v, ss);
  }
  __shared__ float red[8][64];
  red[q][c] = s;
  red[4 + q][c] = ss;
  __syncthreads();
  if (q == 0) {
    float S = red[0][c] + red[1][c] + red[2][c] + red[3][c];
    float SS = red[4][c] + red[5][c] + red[6][c] + red[7][c];
    atomicAdd(&sums[c], S);
    atomicAdd(&sums[64 + c], SS);
  }
}

// ---------------- K4: finalize BN1 ----------------
__global__ void k_fin1(const float* __restrict__ sums, const float* __restrict__ b1,
                       const float* __restrict__ g1, const float* __restrict__ be1,
                       float* __restrict__ ST) {
  int o = threadIdx.x;
  const float E = 327680.f;
  float m = sums[o] / E;
  float var = fmaxf(sums[64 + o] / E - m * m, 0.f);
  float s = g1[o] / sqrtf(var + EPS_);
  ST[o] = s;
  ST[64 + o] = be1[o] + (b1[o] - m) * s;
}

// ---------------- K5: layer-2 matvec + BN2 stats + per-point max/min ------
__global__ __launch_bounds__(256, 2) void k_layer2(
    const float* __restrict__ A, const float* __restrict__ Cc,
    const int* __restrict__ idx, const float* __restrict__ ST1,
    const float* __restrict__ w2, const float* __restrict__ b2,
    float* __restrict__ ymax, float* __restrict__ ymin,
    float* __restrict__ sums2) {
  const int tid = threadIdx.x;
  const int lane = tid & 63, w = tid >> 6;
  float w2r[64];
#pragma unroll
  for (int c = 0; c < 64; ++c) w2r[c] = w2[lane * 64 + c];
  const float S1l = ST1[lane], T1l = ST1[64 + lane], b2l = b2[lane];
  float psum = 0.f, pss = 0.f;
  for (int it = 0; it < 4; ++it) {
    int p = blockIdx.x * 16 + w * 4 + it;
    int b = p >> 12;
    float cc = Cc[(size_t)p * 64 + lane];
    float mx = -FLT_MAX, mn = FLT_MAX;
    for (int kk = 0; kk < 20; ++kk) {
      int j = idx[p * 20 + kk];
      float a = A[(((size_t)b << 12) + j) * 64 + lane];
      float h = fmaxf(0.f, fmaf(a + cc, S1l, T1l));
      int hb = __float_as_int(h);
      float y = b2l;
#pragma unroll
      for (int c = 0; c < 64; ++c) {
        float hc = __int_as_float(__builtin_amdgcn_readlane(hb, c));
        y = fmaf(w2r[c], hc, y);
      }
      mx = fmaxf(mx, y);
      mn = fminf(mn, y);
      psum += y;
      pss = fmaf(y, y, pss);
    }
    ymax[(size_t)p * 64 + lane] = mx;
    ymin[(size_t)p * 64 + lane] = mn;
  }
  __shared__ float red2[8][64];
  red2[w][lane] = psum;
  red2[4 + w][lane] = pss;
  __syncthreads();
  if (w == 0) {
    float S = red2[0][lane] + red2[1][lane] + red2[2][lane] + red2[3][lane];
    float SS = red2[4][lane] + red2[5][lane] + red2[6][lane] + red2[7][lane];
    atomicAdd(&sums2[lane], S);
    atomicAdd(&sums2[64 + lane], SS);
  }
}

// ---------------- K6a: finalize BN2 ----------------
__global__ void k_fin2(const float* __restrict__ sums2, const float* __restrict__ g2,
                       const float* __restrict__ be2, float* __restrict__ ST2) {
  int o = threadIdx.x;
  const float E = 327680.f;
  float m = sums2[o] / E;
  float var = fmaxf(sums2[64 + o] / E - m * m, 0.f);
  float s = g2[o] / sqrtf(var + EPS_);
  ST2[o] = s;
  ST2[64 + o] = be2[o] - m * s;
}

// ---------------- K6b: epilogue out[b][o][n] ----------------
__global__ __launch_bounds__(256) void k_out(const float* __restrict__ ymax,
                                             const float* __restrict__ ymin,
                                             const float* __restrict__ ST2,
                                             float* __restrict__ out) {
  int t = blockIdx.x * 256 + threadIdx.x;
  int n = t & 4095;
  int o = (t >> 12) & 63;
  int b = t >> 18;
  float s = ST2[o], tt = ST2[64 + o];
  size_t p = ((size_t)b << 12) + n;
  float v = (s >= 0.f) ? ymax[p * 64 + o] : ymin[p * 64 + o];
  out[t] = fmaxf(0.f, fmaf(v, s, tt));
}

extern "C" void kernel_launch(void* const* d_in, const int* in_sizes, int n_in,
                              void* d_out, int out_size, void* d_ws, size_t ws_size,
                              hipStream_t stream) {
  const float* x   = (const float*)d_in[0];
  const float* w1  = (const float*)d_in[1];
  const float* b1  = (const float*)d_in[2];
  const float* g1  = (const float*)d_in[3];
  const float* be1 = (const float*)d_in[4];
  const float* w2  = (const float*)d_in[5];
  const float* b2  = (const float*)d_in[6];
  const float* g2  = (const float*)d_in[7];
  const float* be2 = (const float*)d_in[8];
  float* out = (float*)d_out;
  float* ws = (float*)d_ws;

  float* xx   = ws + OFF_XX;
  float* A    = ws + OFF_A;
  float* Cc   = ws + OFF_CC;
  float* ymax = ws + OFF_YMAX;
  float* ymin = ws + OFF_YMIN;
  float* sums = ws + OFF_SUMS;
  float* ST1  = ws + OFF_ST;
  float* ST2  = ST1 + 128;
  int*   idx  = (int*)(ws + OFF_IDX);
  float* xt   = ws + OFF_XT;            // aliases ymax (dead until k_layer2)
  ushort* Phi = (ushort*)(ws + OFF_PHI);// aliases ymin
  ushort* Plo = (ushort*)(ws + OFF_PLO);

  hipMemsetAsync(sums, 0, 256 * sizeof(float), stream);

  k_xx    <<<64,   256, 0, stream>>>(x, xx);
  k_xt    <<<4096, 256, 0, stream>>>(x, xt);
  k_pack  <<<512,  256, 0, stream>>>(x, Phi, Plo);
  k_aw    <<<4096, 256, 0, stream>>>(x, w1, A, Cc);
  k_knn2  <<<512,  256, 0, stream>>>(Phi, Plo, xx, xt, idx);
  k_stats1<<<2560, 256, 0, stream>>>(A, Cc, idx, b1, sums);
  k_fin1  <<<1,    64,  0, stream>>>(sums, b1, g1, be1, ST1);
  k_layer2<<<1024, 256, 0, stream>>>(A, Cc, idx, ST1, w2, b2, ymax, ymin, sums + 128);
  k_fin2  <<<1,    64,  0, stream>>>(sums + 128, g2, be2, ST2);
  k_out   <<<4096, 256, 0, stream>>>(ymax, ymin, ST2, out);
}

// Round 3
// 352.381 us; speedup vs baseline: 1.6834x; 1.2886x over previous
//
#include <hip/hip_runtime.h>
#include <float.h>

#define B_ 4
#define C_ 64
#define N_ 4096
#define O_ 64
#define K_ 20
#define EPS_ 1e-5f

typedef float f32x4 __attribute__((ext_vector_type(4)));
typedef short s16x8 __attribute__((ext_vector_type(8)));

union Frag { uint4 u; s16x8 s; };

// ws layout (in float slots)
#define OFF_XX   ((size_t)0)              // 16384
#define OFF_A    ((size_t)16384)          // 1048576
#define OFF_CC   ((size_t)1064960)        // 1048576
#define OFF_YMAX ((size_t)2113536)        // 1048576  (xt lives here until k_layer2)
#define OFF_YMIN ((size_t)3162112)        // 1048576  (Phi+Plo live here until k_layer2)
#define OFF_SUMS ((size_t)4210688)        // 256
#define OFF_ST   ((size_t)4210944)        // 256
#define OFF_IDX  ((size_t)4211200)        // 327680 ints
#define OFF_XT   OFF_YMAX
#define OFF_PHI  OFF_YMIN
#define OFF_PLO  (OFF_YMIN + 524288)

__device__ inline ushort f2bf(float f) {
  uint u = __float_as_uint(f);
  return (ushort)((u + 0x7fffu + ((u >> 16) & 1u)) >> 16);
}
__device__ inline float bf2f(ushort h) { return __uint_as_float(((uint)h) << 16); }

// ---------------- K0: fused prep: xx, xt, Phi, Plo from one x read --------
// 256 blocks = (b, 64-point tile). 256 thr.
__global__ __launch_bounds__(256) void k_prep(const float* __restrict__ x,
                                              float* __restrict__ xx,
                                              float* __restrict__ xt,
                                              ushort* __restrict__ Phi,
                                              ushort* __restrict__ Plo) {
  __shared__ float lds[64 * 65];
  const int tid = threadIdx.x;
  const int b = blockIdx.x >> 6;
  const int n0 = (blockIdx.x & 63) << 6;
  const int bN = b << 12;
  const int nl = tid & 63;
  const int rbase = (tid >> 6) * 16;
#pragma unroll
  for (int r = 0; r < 16; ++r) {
    int c = rbase + r;
    lds[c * 65 + nl] = x[((size_t)(b * 64 + c)) * N_ + n0 + nl];
  }
  __syncthreads();

  // xt[b][n][c]: thread handles point p = tid/4, c0 = (tid&3)*16
  {
    int p = tid >> 2, c0 = (tid & 3) << 4;
#pragma unroll
    for (int q = 0; q < 4; ++q) {
      float4 v;
      v.x = lds[(c0 + q * 4 + 0) * 65 + p];
      v.y = lds[(c0 + q * 4 + 1) * 65 + p];
      v.z = lds[(c0 + q * 4 + 2) * 65 + p];
      v.w = lds[(c0 + q * 4 + 3) * 65 + p];
      *(float4*)(xt + ((size_t)(bN + n0 + p)) * 64 + c0 + q * 4) = v;
    }
  }

  // bf16 hi/lo pack in MFMA fragment order: wave w -> n-tile (n0>>4)+w
  {
    const int lane = tid & 63, w = tid >> 6;
    const int nloc = w * 16 + (lane & 15);
    const int gnt = (n0 >> 4) + w;
#pragma unroll
    for (int kt = 0; kt < 2; ++kt) {
      int cbase = kt * 32 + ((lane >> 4) << 3);
      ushort hi[8], lo[8];
#pragma unroll
      for (int e = 0; e < 8; ++e) {
        float v = lds[(cbase + e) * 65 + nloc];
        ushort h = f2bf(v);
        float l = v - bf2f(h);
        hi[e] = h;
        lo[e] = f2bf(l);
      }
      size_t base = ((size_t)((b * 256 + gnt) * 2 + kt)) * 512 + lane * 8;
      uint4 uh, ul;
      uh.x = hi[0] | ((uint)hi[1] << 16); uh.y = hi[2] | ((uint)hi[3] << 16);
      uh.z = hi[4] | ((uint)hi[5] << 16); uh.w = hi[6] | ((uint)hi[7] << 16);
      ul.x = lo[0] | ((uint)lo[1] << 16); ul.y = lo[2] | ((uint)lo[3] << 16);
      ul.z = lo[4] | ((uint)lo[5] << 16); ul.w = lo[6] | ((uint)lo[7] << 16);
      *(uint4*)(Phi + base) = uh;
      *(uint4*)(Plo + base) = ul;
    }
  }

  // xx (exact fp32, same order as before: c ascending)
  if (tid < 64) {
    float acc = 0.f;
#pragma unroll
    for (int c = 0; c < 64; ++c) {
      float v = lds[c * 65 + tid];
      acc = fmaf(v, v, acc);
    }
    xx[bN + n0 + tid] = acc;
  }
}

// ---------------- K1: kNN via MFMA + histogram threshold + exact refine ---
// 512 blocks: (b, i-tile of 32 rows). 512 thr = 8 waves, j-stride 8.
__global__ __launch_bounds__(512, 4) void k_knn2(
    const ushort* __restrict__ Phi, const ushort* __restrict__ Plo,
    const float* __restrict__ xx, const float* __restrict__ xt,
    int* __restrict__ idxout) {
  __shared__ uint  hist[32 * 257];   // 32.9 KB
  __shared__ float xi[32 * 64];      // 8 KB
  __shared__ float xxi[32];
  __shared__ float Tsh[32];
  __shared__ uint  cnt[32];
  __shared__ int   cand[32 * 64];    // 8 KB

  const int tid = threadIdx.x;
  const int lane = tid & 63, w = tid >> 6;    // w: 0..7
  const int b = blockIdx.x >> 7;
  const int i0 = (blockIdx.x & 127) << 5;
  const int bN = b << 12;

  for (int i = tid; i < 32 * 257; i += 512) hist[i] = 0;
  if (tid < 32) { xxi[tid] = xx[bN + i0 + tid]; cnt[tid] = 0; }
  {
    int f0 = tid * 4;
    const float* src = xt + ((size_t)bN + i0 + (f0 >> 6)) * 64 + (f0 & 63);
#pragma unroll
    for (int e = 0; e < 4; ++e) xi[f0 + e] = src[e];
  }
  __syncthreads();

  // A fragments (per wave: both 16-row subtiles, both k-tiles, hi+lo)
  Frag ahi[2][2], alo[2][2];
#pragma unroll
  for (int isub = 0; isub < 2; ++isub) {
    int nt = (i0 >> 4) + isub;
#pragma unroll
    for (int kt = 0; kt < 2; ++kt) {
      size_t off = ((size_t)((b * 256 + nt) * 2 + kt)) * 512 + lane * 8;
      ahi[isub][kt].u = *(const uint4*)(Phi + off);
      alo[isub][kt].u = *(const uint4*)(Plo + off);
    }
  }
  float xxr[8];
#pragma unroll
  for (int isub = 0; isub < 2; ++isub)
#pragma unroll
    for (int r = 0; r < 4; ++r)
      xxr[isub * 4 + r] = xxi[isub * 16 + ((lane >> 4) << 2) + r];

  struct BTile { Frag h0, h1, l0, l1; float xxj; };

  auto loadB = [&](int js, BTile& t) {
    size_t off0 = ((size_t)((b * 256 + js) * 2)) * 512 + lane * 8;
    t.h0.u = *(const uint4*)(Phi + off0);
    t.h1.u = *(const uint4*)(Phi + off0 + 512);
    t.l0.u = *(const uint4*)(Plo + off0);
    t.l1.u = *(const uint4*)(Plo + off0 + 512);
    t.xxj = xx[bN + js * 16 + (lane & 15)];
  };

  auto compute = [&](int js, const BTile& t, int pass) {
    const int jme = js * 16 + (lane & 15);
#pragma unroll
    for (int isub = 0; isub < 2; ++isub) {
      f32x4 acc = {0.f, 0.f, 0.f, 0.f};
      acc = __builtin_amdgcn_mfma_f32_16x16x32_bf16(ahi[isub][0].s, t.h0.s, acc, 0, 0, 0);
      acc = __builtin_amdgcn_mfma_f32_16x16x32_bf16(ahi[isub][1].s, t.h1.s, acc, 0, 0, 0);
      acc = __builtin_amdgcn_mfma_f32_16x16x32_bf16(ahi[isub][0].s, t.l0.s, acc, 0, 0, 0);
      acc = __builtin_amdgcn_mfma_f32_16x16x32_bf16(ahi[isub][1].s, t.l1.s, acc, 0, 0, 0);
      acc = __builtin_amdgcn_mfma_f32_16x16x32_bf16(alo[isub][0].s, t.h0.s, acc, 0, 0, 0);
      acc = __builtin_amdgcn_mfma_f32_16x16x32_bf16(alo[isub][1].s, t.h1.s, acc, 0, 0, 0);
#pragma unroll
      for (int r = 0; r < 4; ++r) {
        int rowl = isub * 16 + ((lane >> 4) << 2) + r;
        float d = fmaf(-2.f, acc[r], xxr[isub * 4 + r]) + t.xxj;
        if (pass == 0) {
          int bk = (int)d;
          bk = bk < 0 ? 0 : (bk > 255 ? 255 : bk);
          atomicAdd(&hist[rowl * 257 + bk], 1u);
        } else {
          if (d <= Tsh[rowl]) {
            uint pos = atomicAdd(&cnt[rowl], 1u);
            if (pos < 64) cand[rowl * 64 + pos] = jme;
          }
        }
      }
    }
  };

  for (int pass = 0; pass < 2; ++pass) {
    BTile t0, t1;
    loadB(w, t0);
    for (int js = w; js < 256; js += 16) {
      loadB(js + 8, t1);                 // js+8 <= 255 always
      compute(js, t0, pass);
      if (js + 16 < 256) loadB(js + 16, t0);
      compute(js + 8, t1, pass);
    }
    __syncthreads();
    if (pass == 0) {
      if (tid < 32) {
        uint cum = 0;
        int tb = 255;
        for (int k = 0; k < 256; ++k) {
          cum += hist[tid * 257 + k];
          if (cum >= 20u && tb == 255) tb = k;
        }
        Tsh[tid] = (float)(tb + 1) + 0.25f;
      }
      __syncthreads();
    }
  }

  // exact refine + bitonic top-20 (4 rows per wave)
  for (int rr = 0; rr < 4; ++rr) {
    const int row = w * 4 + rr;
    const int nc = (int)min(cnt[row], 64u);
    unsigned long long key = ~0ULL;
    if (lane < nc) {
      int j = cand[row * 64 + lane];
      const float* xj = xt + ((size_t)bN + j) * 64;
      const float* xic = &xi[row * 64];
      float dot = 0.f;
#pragma unroll 8
      for (int c = 0; c < 64; ++c) dot = fmaf(xic[c], xj[c], dot);
      float dex = (xxi[row] - 2.f * dot) + xx[bN + j];
      uint fb = __float_as_uint(dex);
      fb = (fb & 0x80000000u) ? ~fb : (fb | 0x80000000u);
      key = (((unsigned long long)fb) << 32) | (uint)j;
    }
#pragma unroll
    for (int k2 = 2; k2 <= 64; k2 <<= 1) {
#pragma unroll
      for (int mm = k2 >> 1; mm >= 1; mm >>= 1) {
        uint klo = (uint)key, khi = (uint)(key >> 32);
        uint olo = __shfl_xor((int)klo, mm, 64);
        uint ohi = __shfl_xor((int)khi, mm, 64);
        unsigned long long o = (((unsigned long long)ohi) << 32) | olo;
        bool up = ((lane & k2) == 0);
        bool lowhalf = ((lane & mm) == 0);
        bool keepmin = (up == lowhalf);
        key = keepmin ? (key < o ? key : o) : (key > o ? key : o);
      }
    }
    if (lane < 20) idxout[((size_t)bN + i0 + row) * 20 + lane] = (int)(uint)key;
  }
}

// ---------------- K2: A = w1a.x, Cc = (w1b-w1a).x, layout [b][n][o] -------
__global__ __launch_bounds__(256) void k_aw(const float* __restrict__ x,
                                            const float* __restrict__ w1,
                                            float* __restrict__ A,
                                            float* __restrict__ Cc) {
  int t = blockIdx.x * 256 + threadIdx.x;
  int o = t & 63;
  int p = t >> 6;
  int n = p & 4095, b = p >> 12;
  const float* xp = x + (size_t)b * C_ * N_ + n;
  const float* wp = w1 + o * 128;
  float a = 0.f, cc = 0.f;
#pragma unroll 8
  for (int c = 0; c < 64; ++c) {
    float xv = xp[c * N_];
    float wA = wp[c], wB = wp[64 + c];
    a = fmaf(xv, wA, a);
    cc = fmaf(xv, wB - wA, cc);
  }
  A[t] = a;
  Cc[t] = cc;
}

// ---------------- K3: BN1 stats ----------------
__global__ __launch_bounds__(256) void k_stats1(const float* __restrict__ A,
                                                const float* __restrict__ Cc,
                                                const int* __restrict__ idx,
                                                const float* __restrict__ b1,
                                                float* __restrict__ sums) {
  int tid = threadIdx.x;
  int c = tid & 63, q = tid >> 6;
  float b1c = b1[c];
  float s = 0.f, ss = 0.f;
  int ebase = blockIdx.x * 128 + q * 32;
  for (int it = 0; it < 32; ++it) {
    int e = ebase + it;
    int pl = e / 20;
    int b = pl >> 12;
    int j = idx[e];
    float v = A[(((size_t)b << 12) + j) * 64 + c] + Cc[(size_t)pl * 64 + c] + b1c;
    s += v;
    ss = fmaf(v, v, ss);
  }
  __shared__ float red[8][64];
  red[q][c] = s;
  red[4 + q][c] = ss;
  __syncthreads();
  if (q == 0) {
    float S = red[0][c] + red[1][c] + red[2][c] + red[3][c];
    float SS = red[4][c] + red[5][c] + red[6][c] + red[7][c];
    atomicAdd(&sums[c], S);
    atomicAdd(&sums[64 + c], SS);
  }
}

// ---------------- K4: finalize BN1 ----------------
__global__ void k_fin1(const float* __restrict__ sums, const float* __restrict__ b1,
                       const float* __restrict__ g1, const float* __restrict__ be1,
                       float* __restrict__ ST) {
  int o = threadIdx.x;
  const float E = 327680.f;
  float m = sums[o] / E;
  float var = fmaxf(sums[64 + o] / E - m * m, 0.f);
  float s = g1[o] / sqrtf(var + EPS_);
  ST[o] = s;
  ST[64 + o] = be1[o] + (b1[o] - m) * s;
}

// ---------------- K5: layer-2 matvec + BN2 stats + per-point max/min ------
__global__ __launch_bounds__(256, 2) void k_layer2(
    const float* __restrict__ A, const float* __restrict__ Cc,
    const int* __restrict__ idx, const float* __restrict__ ST1,
    const float* __restrict__ w2, const float* __restrict__ b2,
    float* __restrict__ ymax, float* __restrict__ ymin,
    float* __restrict__ sums2) {
  const int tid = threadIdx.x;
  const int lane = tid & 63, w = tid >> 6;
  float w2r[64];
#pragma unroll
  for (int c = 0; c < 64; ++c) w2r[c] = w2[lane * 64 + c];
  const float S1l = ST1[lane], T1l = ST1[64 + lane], b2l = b2[lane];
  float psum = 0.f, pss = 0.f;
  for (int it = 0; it < 4; ++it) {
    int p = blockIdx.x * 16 + w * 4 + it;
    int b = p >> 12;
    float cc = Cc[(size_t)p * 64 + lane];
    float mx = -FLT_MAX, mn = FLT_MAX;
    for (int kk = 0; kk < 20; ++kk) {
      int j = idx[p * 20 + kk];
      float a = A[(((size_t)b << 12) + j) * 64 + lane];
      float h = fmaxf(0.f, fmaf(a + cc, S1l, T1l));
      int hb = __float_as_int(h);
      float y = b2l;
#pragma unroll
      for (int c = 0; c < 64; ++c) {
        float hc = __int_as_float(__builtin_amdgcn_readlane(hb, c));
        y = fmaf(w2r[c], hc, y);
      }
      mx = fmaxf(mx, y);
      mn = fminf(mn, y);
      psum += y;
      pss = fmaf(y, y, pss);
    }
    ymax[(size_t)p * 64 + lane] = mx;
    ymin[(size_t)p * 64 + lane] = mn;
  }
  __shared__ float red2[8][64];
  red2[w][lane] = psum;
  red2[4 + w][lane] = pss;
  __syncthreads();
  if (w == 0) {
    float S = red2[0][lane] + red2[1][lane] + red2[2][lane] + red2[3][lane];
    float SS = red2[4][lane] + red2[5][lane] + red2[6][lane] + red2[7][lane];
    atomicAdd(&sums2[lane], S);
    atomicAdd(&sums2[64 + lane], SS);
  }
}

// ---------------- K6a: finalize BN2 ----------------
__global__ void k_fin2(const float* __restrict__ sums2, const float* __restrict__ g2,
                       const float* __restrict__ be2, float* __restrict__ ST2) {
  int o = threadIdx.x;
  const float E = 327680.f;
  float m = sums2[o] / E;
  float var = fmaxf(sums2[64 + o] / E - m * m, 0.f);
  float s = g2[o] / sqrtf(var + EPS_);
  ST2[o] = s;
  ST2[64 + o] = be2[o] - m * s;
}

// ---------------- K6b: epilogue out[b][o][n] ----------------
__global__ __launch_bounds__(256) void k_out(const float* __restrict__ ymax,
                                             const float* __restrict__ ymin,
                                             const float* __restrict__ ST2,
                                             float* __restrict__ out) {
  int t = blockIdx.x * 256 + threadIdx.x;
  int n = t & 4095;
  int o = (t >> 12) & 63;
  int b = t >> 18;
  float s = ST2[o], tt = ST2[64 + o];
  size_t p = ((size_t)b << 12) + n;
  float v = (s >= 0.f) ? ymax[p * 64 + o] : ymin[p * 64 + o];
  out[t] = fmaxf(0.f, fmaf(v, s, tt));
}

extern "C" void kernel_launch(void* const* d_in, const int* in_sizes, int n_in,
                              void* d_out, int out_size, void* d_ws, size_t ws_size,
                              hipStream_t stream) {
  const float* x   = (const float*)d_in[0];
  const float* w1  = (const float*)d_in[1];
  const float* b1  = (const float*)d_in[2];
  const float* g1  = (const float*)d_in[3];
  const float* be1 = (const float*)d_in[4];
  const float* w2  = (const float*)d_in[5];
  const float* b2  = (const float*)d_in[6];
  const float* g2  = (const float*)d_in[7];
  const float* be2 = (const float*)d_in[8];
  float* out = (float*)d_out;
  float* ws = (float*)d_ws;

  float* xx   = ws + OFF_XX;
  float* A    = ws + OFF_A;
  float* Cc   = ws + OFF_CC;
  float* ymax = ws + OFF_YMAX;
  float* ymin = ws + OFF_YMIN;
  float* sums = ws + OFF_SUMS;
  float* ST1  = ws + OFF_ST;
  float* ST2  = ST1 + 128;
  int*   idx  = (int*)(ws + OFF_IDX);
  float* xt   = ws + OFF_XT;
  ushort* Phi = (ushort*)(ws + OFF_PHI);
  ushort* Plo = (ushort*)(ws + OFF_PLO);

  hipMemsetAsync(sums, 0, 256 * sizeof(float), stream);

  k_prep  <<<256,  256, 0, stream>>>(x, xx, xt, Phi, Plo);
  k_aw    <<<4096, 256, 0, stream>>>(x, w1, A, Cc);
  k_knn2  <<<512,  512, 0, stream>>>(Phi, Plo, xx, xt, idx);
  k_stats1<<<2560, 256, 0, stream>>>(A, Cc, idx, b1, sums);
  k_fin1  <<<1,    64,  0, stream>>>(sums, b1, g1, be1, ST1);
  k_layer2<<<1024, 256, 0, stream>>>(A, Cc, idx, ST1, w2, b2, ymax, ymin, sums + 128);
  k_fin2  <<<1,    64,  0, stream>>>(sums + 128, g2, be2, ST2);
  k_out   <<<4096, 256, 0, stream>>>(ymax, ymin, ST2, out);
}

// Round 4
// 322.836 us; speedup vs baseline: 1.8375x; 1.0915x over previous
//
#include <hip/hip_runtime.h>
#include <float.h>

#define B_ 4
#define C_ 64
#define N_ 4096
#define O_ 64
#define K_ 20
#define EPS_ 1e-5f

typedef float f32x4 __attribute__((ext_vector_type(4)));
typedef short s16x8 __attribute__((ext_vector_type(8)));

union Frag { uint4 u; s16x8 s; };

// ws layout (in float slots)
#define OFF_XX   ((size_t)0)              // 16384 (dead after k_knn2; w2p aliases it)
#define OFF_A    ((size_t)16384)          // 1048576
#define OFF_CC   ((size_t)1064960)        // 1048576
#define OFF_YMAX ((size_t)2113536)        // 1048576  (xt lives here until k_l2m)
#define OFF_YMIN ((size_t)3162112)        // 1048576  (Phi+Plo live here until k_l2m)
#define OFF_SUMS ((size_t)4210688)        // 256
#define OFF_ST   ((size_t)4210944)        // 256
#define OFF_IDX  ((size_t)4211200)        // 327680 ints
#define OFF_XT   OFF_YMAX
#define OFF_PHI  OFF_YMIN
#define OFF_PLO  (OFF_YMIN + 524288)
#define OFF_W2P  OFF_XX                   // 8192 ushorts, written by k_fin1 (xx dead)

__device__ inline ushort f2bf(float f) {
  uint u = __float_as_uint(f);
  return (ushort)((u + 0x7fffu + ((u >> 16) & 1u)) >> 16);
}
__device__ inline float bf2f(ushort h) { return __uint_as_float(((uint)h) << 16); }

// ---------------- K0: fused prep: xx, xt, Phi, Plo from one x read --------
__global__ __launch_bounds__(256) void k_prep(const float* __restrict__ x,
                                              float* __restrict__ xx,
                                              float* __restrict__ xt,
                                              ushort* __restrict__ Phi,
                                              ushort* __restrict__ Plo) {
  __shared__ float lds[64 * 65];
  const int tid = threadIdx.x;
  const int b = blockIdx.x >> 6;
  const int n0 = (blockIdx.x & 63) << 6;
  const int bN = b << 12;
  const int nl = tid & 63;
  const int rbase = (tid >> 6) * 16;
#pragma unroll
  for (int r = 0; r < 16; ++r) {
    int c = rbase + r;
    lds[c * 65 + nl] = x[((size_t)(b * 64 + c)) * N_ + n0 + nl];
  }
  __syncthreads();

  {
    int p = tid >> 2, c0 = (tid & 3) << 4;
#pragma unroll
    for (int q = 0; q < 4; ++q) {
      float4 v;
      v.x = lds[(c0 + q * 4 + 0) * 65 + p];
      v.y = lds[(c0 + q * 4 + 1) * 65 + p];
      v.z = lds[(c0 + q * 4 + 2) * 65 + p];
      v.w = lds[(c0 + q * 4 + 3) * 65 + p];
      *(float4*)(xt + ((size_t)(bN + n0 + p)) * 64 + c0 + q * 4) = v;
    }
  }

  {
    const int lane = tid & 63, w = tid >> 6;
    const int nloc = w * 16 + (lane & 15);
    const int gnt = (n0 >> 4) + w;
#pragma unroll
    for (int kt = 0; kt < 2; ++kt) {
      int cbase = kt * 32 + ((lane >> 4) << 3);
      ushort hi[8], lo[8];
#pragma unroll
      for (int e = 0; e < 8; ++e) {
        float v = lds[(cbase + e) * 65 + nloc];
        ushort h = f2bf(v);
        float l = v - bf2f(h);
        hi[e] = h;
        lo[e] = f2bf(l);
      }
      size_t base = ((size_t)((b * 256 + gnt) * 2 + kt)) * 512 + lane * 8;
      uint4 uh, ul;
      uh.x = hi[0] | ((uint)hi[1] << 16); uh.y = hi[2] | ((uint)hi[3] << 16);
      uh.z = hi[4] | ((uint)hi[5] << 16); uh.w = hi[6] | ((uint)hi[7] << 16);
      ul.x = lo[0] | ((uint)lo[1] << 16); ul.y = lo[2] | ((uint)lo[3] << 16);
      ul.z = lo[4] | ((uint)lo[5] << 16); ul.w = lo[6] | ((uint)lo[7] << 16);
      *(uint4*)(Phi + base) = uh;
      *(uint4*)(Plo + base) = ul;
    }
  }

  if (tid < 64) {
    float acc = 0.f;
#pragma unroll
    for (int c = 0; c < 64; ++c) {
      float v = lds[c * 65 + tid];
      acc = fmaf(v, v, acc);
    }
    xx[bN + n0 + tid] = acc;
  }
}

// ---------------- K1: kNN via MFMA + histogram threshold + exact refine ---
__global__ __launch_bounds__(512, 4) void k_knn2(
    const ushort* __restrict__ Phi, const ushort* __restrict__ Plo,
    const float* __restrict__ xx, const float* __restrict__ xt,
    int* __restrict__ idxout) {
  __shared__ uint  hist[32 * 257];
  __shared__ float xi[32 * 64];
  __shared__ float xxi[32];
  __shared__ float Tsh[32];
  __shared__ uint  cnt[32];
  __shared__ int   cand[32 * 64];

  const int tid = threadIdx.x;
  const int lane = tid & 63, w = tid >> 6;
  const int b = blockIdx.x >> 7;
  const int i0 = (blockIdx.x & 127) << 5;
  const int bN = b << 12;

  for (int i = tid; i < 32 * 257; i += 512) hist[i] = 0;
  if (tid < 32) { xxi[tid] = xx[bN + i0 + tid]; cnt[tid] = 0; }
  {
    int f0 = tid * 4;
    const float* src = xt + ((size_t)bN + i0 + (f0 >> 6)) * 64 + (f0 & 63);
#pragma unroll
    for (int e = 0; e < 4; ++e) xi[f0 + e] = src[e];
  }
  __syncthreads();

  Frag ahi[2][2], alo[2][2];
#pragma unroll
  for (int isub = 0; isub < 2; ++isub) {
    int nt = (i0 >> 4) + isub;
#pragma unroll
    for (int kt = 0; kt < 2; ++kt) {
      size_t off = ((size_t)((b * 256 + nt) * 2 + kt)) * 512 + lane * 8;
      ahi[isub][kt].u = *(const uint4*)(Phi + off);
      alo[isub][kt].u = *(const uint4*)(Plo + off);
    }
  }
  float xxr[8];
#pragma unroll
  for (int isub = 0; isub < 2; ++isub)
#pragma unroll
    for (int r = 0; r < 4; ++r)
      xxr[isub * 4 + r] = xxi[isub * 16 + ((lane >> 4) << 2) + r];

  struct BTile { Frag h0, h1, l0, l1; float xxj; };

  auto loadB = [&](int js, BTile& t) {
    size_t off0 = ((size_t)((b * 256 + js) * 2)) * 512 + lane * 8;
    t.h0.u = *(const uint4*)(Phi + off0);
    t.h1.u = *(const uint4*)(Phi + off0 + 512);
    t.l0.u = *(const uint4*)(Plo + off0);
    t.l1.u = *(const uint4*)(Plo + off0 + 512);
    t.xxj = xx[bN + js * 16 + (lane & 15)];
  };

  auto compute = [&](int js, const BTile& t, int pass) {
    const int jme = js * 16 + (lane & 15);
#pragma unroll
    for (int isub = 0; isub < 2; ++isub) {
      f32x4 acc = {0.f, 0.f, 0.f, 0.f};
      acc = __builtin_amdgcn_mfma_f32_16x16x32_bf16(ahi[isub][0].s, t.h0.s, acc, 0, 0, 0);
      acc = __builtin_amdgcn_mfma_f32_16x16x32_bf16(ahi[isub][1].s, t.h1.s, acc, 0, 0, 0);
      acc = __builtin_amdgcn_mfma_f32_16x16x32_bf16(ahi[isub][0].s, t.l0.s, acc, 0, 0, 0);
      acc = __builtin_amdgcn_mfma_f32_16x16x32_bf16(ahi[isub][1].s, t.l1.s, acc, 0, 0, 0);
      acc = __builtin_amdgcn_mfma_f32_16x16x32_bf16(alo[isub][0].s, t.h0.s, acc, 0, 0, 0);
      acc = __builtin_amdgcn_mfma_f32_16x16x32_bf16(alo[isub][1].s, t.h1.s, acc, 0, 0, 0);
#pragma unroll
      for (int r = 0; r < 4; ++r) {
        int rowl = isub * 16 + ((lane >> 4) << 2) + r;
        float d = fmaf(-2.f, acc[r], xxr[isub * 4 + r]) + t.xxj;
        if (pass == 0) {
          int bk = (int)d;
          bk = bk < 0 ? 0 : (bk > 255 ? 255 : bk);
          atomicAdd(&hist[rowl * 257 + bk], 1u);
        } else {
          if (d <= Tsh[rowl]) {
            uint pos = atomicAdd(&cnt[rowl], 1u);
            if (pos < 64) cand[rowl * 64 + pos] = jme;
          }
        }
      }
    }
  };

  for (int pass = 0; pass < 2; ++pass) {
    BTile t0, t1;
    loadB(w, t0);
    for (int js = w; js < 256; js += 16) {
      loadB(js + 8, t1);
      compute(js, t0, pass);
      if (js + 16 < 256) loadB(js + 16, t0);
      compute(js + 8, t1, pass);
    }
    __syncthreads();
    if (pass == 0) {
      if (tid < 32) {
        uint cum = 0;
        int tb = 255;
        for (int k = 0; k < 256; ++k) {
          cum += hist[tid * 257 + k];
          if (cum >= 20u && tb == 255) tb = k;
        }
        Tsh[tid] = (float)(tb + 1) + 0.25f;
      }
      __syncthreads();
    }
  }

  for (int rr = 0; rr < 4; ++rr) {
    const int row = w * 4 + rr;
    const int nc = (int)min(cnt[row], 64u);
    unsigned long long key = ~0ULL;
    if (lane < nc) {
      int j = cand[row * 64 + lane];
      const float* xj = xt + ((size_t)bN + j) * 64;
      const float* xic = &xi[row * 64];
      float dot = 0.f;
#pragma unroll 8
      for (int c = 0; c < 64; ++c) dot = fmaf(xic[c], xj[c], dot);
      float dex = (xxi[row] - 2.f * dot) + xx[bN + j];
      uint fb = __float_as_uint(dex);
      fb = (fb & 0x80000000u) ? ~fb : (fb | 0x80000000u);
      key = (((unsigned long long)fb) << 32) | (uint)j;
    }
#pragma unroll
    for (int k2 = 2; k2 <= 64; k2 <<= 1) {
#pragma unroll
      for (int mm = k2 >> 1; mm >= 1; mm >>= 1) {
        uint klo = (uint)key, khi = (uint)(key >> 32);
        uint olo = __shfl_xor((int)klo, mm, 64);
        uint ohi = __shfl_xor((int)khi, mm, 64);
        unsigned long long o = (((unsigned long long)ohi) << 32) | olo;
        bool up = ((lane & k2) == 0);
        bool lowhalf = ((lane & mm) == 0);
        bool keepmin = (up == lowhalf);
        key = keepmin ? (key < o ? key : o) : (key > o ? key : o);
      }
    }
    if (lane < 20) idxout[((size_t)bN + i0 + row) * 20 + lane] = (int)(uint)key;
  }
}

// ---------------- K2: A = w1a.x, Cc = (w1b-w1a).x, layout [b][n][o] -------
__global__ __launch_bounds__(256) void k_aw(const float* __restrict__ x,
                                            const float* __restrict__ w1,
                                            float* __restrict__ A,
                                            float* __restrict__ Cc) {
  int t = blockIdx.x * 256 + threadIdx.x;
  int o = t & 63;
  int p = t >> 6;
  int n = p & 4095, b = p >> 12;
  const float* xp = x + (size_t)b * C_ * N_ + n;
  const float* wp = w1 + o * 128;
  float a = 0.f, cc = 0.f;
#pragma unroll 8
  for (int c = 0; c < 64; ++c) {
    float xv = xp[c * N_];
    float wA = wp[c], wB = wp[64 + c];
    a = fmaf(xv, wA, a);
    cc = fmaf(xv, wB - wA, cc);
  }
  A[t] = a;
  Cc[t] = cc;
}

// ---------------- K3: BN1 stats ----------------
__global__ __launch_bounds__(256) void k_stats1(const float* __restrict__ A,
                                                const float* __restrict__ Cc,
                                                const int* __restrict__ idx,
                                                const float* __restrict__ b1,
                                                float* __restrict__ sums) {
  int tid = threadIdx.x;
  int c = tid & 63, q = tid >> 6;
  float b1c = b1[c];
  float s = 0.f, ss = 0.f;
  int ebase = blockIdx.x * 128 + q * 32;
  for (int it = 0; it < 32; ++it) {
    int e = ebase + it;
    int pl = e / 20;
    int b = pl >> 12;
    int j = idx[e];
    float v = A[(((size_t)b << 12) + j) * 64 + c] + Cc[(size_t)pl * 64 + c] + b1c;
    s += v;
    ss = fmaf(v, v, ss);
  }
  __shared__ float red[8][64];
  red[q][c] = s;
  red[4 + q][c] = ss;
  __syncthreads();
  if (q == 0) {
    float S = red[0][c] + red[1][c] + red[2][c] + red[3][c];
    float SS = red[4][c] + red[5][c] + red[6][c] + red[7][c];
    atomicAdd(&sums[c], S);
    atomicAdd(&sums[64 + c], SS);
  }
}

// ---------------- K4: finalize BN1 + pack w2 into MFMA frag order ---------
__global__ void k_fin1(const float* __restrict__ sums, const float* __restrict__ b1,
                       const float* __restrict__ g1, const float* __restrict__ be1,
                       const float* __restrict__ w2, float* __restrict__ ST,
                       ushort* __restrict__ w2p) {
  int o = threadIdx.x;   // 0..63
  const float E = 327680.f;
  float m = sums[o] / E;
  float var = fmaxf(sums[64 + o] / E - m * m, 0.f);
  float s = g1[o] / sqrtf(var + EPS_);
  ST[o] = s;
  ST[64 + o] = be1[o] + (b1[o] - m) * s;

  // w2 frags: this thread provides lane=o entries of all (ot,kt) frags.
  // frag layout: col=lane&15 -> output o, k=(lane>>4)*8+e -> channel c.
  const int colp = o & 15, gp = o >> 4;
#pragma unroll
  for (int ot = 0; ot < 4; ++ot) {
#pragma unroll
    for (int kt = 0; kt < 2; ++kt) {
      uint hw[8], lw[8];
#pragma unroll
      for (int e = 0; e < 8; ++e) {
        float v = w2[(ot * 16 + colp) * 64 + kt * 32 + gp * 8 + e];
        ushort hb = f2bf(v);
        float lv = v - bf2f(hb);
        hw[e] = hb;
        lw[e] = f2bf(lv);
      }
      uint4 uh, ul;
      uh.x = hw[0] | (hw[1] << 16); uh.y = hw[2] | (hw[3] << 16);
      uh.z = hw[4] | (hw[5] << 16); uh.w = hw[6] | (hw[7] << 16);
      ul.x = lw[0] | (lw[1] << 16); ul.y = lw[2] | (lw[3] << 16);
      ul.z = lw[4] | (lw[5] << 16); ul.w = lw[6] | (lw[7] << 16);
      int f = (ot * 2 + kt) * 2;
      *(uint4*)(w2p + (size_t)f * 512 + o * 8) = uh;
      *(uint4*)(w2p + (size_t)(f + 1) * 512 + o * 8) = ul;
    }
  }
}

// ---------------- K5: MFMA layer-2 + BN2 stats + per-point max/min --------
// 512 blocks x 256 thr (4 waves); wave handles 8 points.
__global__ __launch_bounds__(256, 2) void k_l2m(
    const float* __restrict__ A, const float* __restrict__ Cc,
    const int* __restrict__ idx, const float* __restrict__ ST1,
    const ushort* __restrict__ w2p, const float* __restrict__ b2,
    float* __restrict__ ymax, float* __restrict__ ymin,
    float* __restrict__ sums2) {
  const int tid = threadIdx.x;
  const int lane = tid & 63, w = tid >> 6;
  const int g = lane >> 4, col = lane & 15;

  Frag wh[4][2], wl[4][2];
#pragma unroll
  for (int ot = 0; ot < 4; ++ot)
#pragma unroll
    for (int kt = 0; kt < 2; ++kt) {
      int f = (ot * 2 + kt) * 2;
      wh[ot][kt].u = *(const uint4*)(w2p + (size_t)f * 512 + lane * 8);
      wl[ot][kt].u = *(const uint4*)(w2p + (size_t)(f + 1) * 512 + lane * 8);
    }

  float S1v[2][8], T1v[2][8];
#pragma unroll
  for (int kt = 0; kt < 2; ++kt) {
    int c0 = kt * 32 + g * 8;
    *(float4*)&S1v[kt][0] = *(const float4*)(ST1 + c0);
    *(float4*)&S1v[kt][4] = *(const float4*)(ST1 + c0 + 4);
    *(float4*)&T1v[kt][0] = *(const float4*)(ST1 + 64 + c0);
    *(float4*)&T1v[kt][4] = *(const float4*)(ST1 + 64 + c0 + 4);
  }
  float b2r[4];
#pragma unroll
  for (int ot = 0; ot < 4; ++ot) b2r[ot] = b2[ot * 16 + col];

  float ps[4] = {0.f, 0.f, 0.f, 0.f}, pss[4] = {0.f, 0.f, 0.f, 0.f};

  for (int it = 0; it < 8; ++it) {
    const int p = (blockIdx.x * 4 + w) * 8 + it;
    const int bbase = (p >> 12) << 12;
    const float* Cp = Cc + (size_t)p * 64;
    float mx[4], mn[4];
#pragma unroll
    for (int ot = 0; ot < 4; ++ot) { mx[ot] = -FLT_MAX; mn[ot] = FLT_MAX; }

#pragma unroll
    for (int t = 0; t < 2; ++t) {
      int kk = t * 16 + col;
      kk = kk > 19 ? 19 : kk;
      int j = idx[p * 20 + kk];
      const float* Ap = A + ((size_t)(bbase + j)) * 64;
      Frag hh[2];
#pragma unroll
      for (int kt = 0; kt < 2; ++kt) {
        int c0 = kt * 32 + g * 8;
        float4 a0 = *(const float4*)(Ap + c0);
        float4 a1 = *(const float4*)(Ap + c0 + 4);
        float4 q0 = *(const float4*)(Cp + c0);
        float4 q1 = *(const float4*)(Cp + c0 + 4);
        float hv[8];
        hv[0] = fmaxf(0.f, fmaf(a0.x + q0.x, S1v[kt][0], T1v[kt][0]));
        hv[1] = fmaxf(0.f, fmaf(a0.y + q0.y, S1v[kt][1], T1v[kt][1]));
        hv[2] = fmaxf(0.f, fmaf(a0.z + q0.z, S1v[kt][2], T1v[kt][2]));
        hv[3] = fmaxf(0.f, fmaf(a0.w + q0.w, S1v[kt][3], T1v[kt][3]));
        hv[4] = fmaxf(0.f, fmaf(a1.x + q1.x, S1v[kt][4], T1v[kt][4]));
        hv[5] = fmaxf(0.f, fmaf(a1.y + q1.y, S1v[kt][5], T1v[kt][5]));
        hv[6] = fmaxf(0.f, fmaf(a1.z + q1.z, S1v[kt][6], T1v[kt][6]));
        hv[7] = fmaxf(0.f, fmaf(a1.w + q1.w, S1v[kt][7], T1v[kt][7]));
        uint4 uh;
        uh.x = f2bf(hv[0]) | ((uint)f2bf(hv[1]) << 16);
        uh.y = f2bf(hv[2]) | ((uint)f2bf(hv[3]) << 16);
        uh.z = f2bf(hv[4]) | ((uint)f2bf(hv[5]) << 16);
        uh.w = f2bf(hv[6]) | ((uint)f2bf(hv[7]) << 16);
        hh[kt].u = uh;
      }
#pragma unroll
      for (int ot = 0; ot < 4; ++ot) {
        f32x4 acc = {0.f, 0.f, 0.f, 0.f};
        acc = __builtin_amdgcn_mfma_f32_16x16x32_bf16(hh[0].s, wh[ot][0].s, acc, 0, 0, 0);
        acc = __builtin_amdgcn_mfma_f32_16x16x32_bf16(hh[1].s, wh[ot][1].s, acc, 0, 0, 0);
        acc = __builtin_amdgcn_mfma_f32_16x16x32_bf16(hh[0].s, wl[ot][0].s, acc, 0, 0, 0);
        acc = __builtin_amdgcn_mfma_f32_16x16x32_bf16(hh[1].s, wl[ot][1].s, acc, 0, 0, 0);
        if (t == 0) {
#pragma unroll
          for (int r = 0; r < 4; ++r) {
            float y = acc[r] + b2r[ot];
            mx[ot] = fmaxf(mx[ot], y);
            mn[ot] = fminf(mn[ot], y);
            ps[ot] += y;
            pss[ot] = fmaf(y, y, pss[ot]);
          }
        } else if (g == 0) {     // rows 16..19 only (kk = 16 + r < 20)
#pragma unroll
          for (int r = 0; r < 4; ++r) {
            float y = acc[r] + b2r[ot];
            mx[ot] = fmaxf(mx[ot], y);
            mn[ot] = fminf(mn[ot], y);
            ps[ot] += y;
            pss[ot] = fmaf(y, y, pss[ot]);
          }
        }
      }
    }

    // per-point cross-group reduce; then lane writes o = lane
#pragma unroll
    for (int ot = 0; ot < 4; ++ot) {
      float v = mx[ot];
      v = fmaxf(v, __shfl_xor(v, 16, 64));
      v = fmaxf(v, __shfl_xor(v, 32, 64));
      mx[ot] = v;
      float u = mn[ot];
      u = fminf(u, __shfl_xor(u, 16, 64));
      u = fminf(u, __shfl_xor(u, 32, 64));
      mn[ot] = u;
    }
    float wmx = mx[0], wmn = mn[0];
    if (g == 1) { wmx = mx[1]; wmn = mn[1]; }
    if (g == 2) { wmx = mx[2]; wmn = mn[2]; }
    if (g == 3) { wmx = mx[3]; wmn = mn[3]; }
    ymax[(size_t)p * 64 + lane] = wmx;
    ymin[(size_t)p * 64 + lane] = wmn;
  }

  // wave-level BN2 stats -> global atomics
#pragma unroll
  for (int ot = 0; ot < 4; ++ot) {
    float s = ps[ot];
    s += __shfl_xor(s, 16, 64);
    s += __shfl_xor(s, 32, 64);
    float q = pss[ot];
    q += __shfl_xor(q, 16, 64);
    q += __shfl_xor(q, 32, 64);
    if (g == ot) {
      atomicAdd(&sums2[ot * 16 + col], s);
      atomicAdd(&sums2[64 + ot * 16 + col], q);
    }
  }
}

// ---------------- K6a: finalize BN2 ----------------
__global__ void k_fin2(const float* __restrict__ sums2, const float* __restrict__ g2,
                       const float* __restrict__ be2, float* __restrict__ ST2) {
  int o = threadIdx.x;
  const float E = 327680.f;
  float m = sums2[o] / E;
  float var = fmaxf(sums2[64 + o] / E - m * m, 0.f);
  float s = g2[o] / sqrtf(var + EPS_);
  ST2[o] = s;
  ST2[64 + o] = be2[o] - m * s;
}

// ---------------- K6b: epilogue out[b][o][n] ----------------
__global__ __launch_bounds__(256) void k_out(const float* __restrict__ ymax,
                                             const float* __restrict__ ymin,
                                             const float* __restrict__ ST2,
                                             float* __restrict__ out) {
  int t = blockIdx.x * 256 + threadIdx.x;
  int n = t & 4095;
  int o = (t >> 12) & 63;
  int b = t >> 18;
  float s = ST2[o], tt = ST2[64 + o];
  size_t p = ((size_t)b << 12) + n;
  float v = (s >= 0.f) ? ymax[p * 64 + o] : ymin[p * 64 + o];
  out[t] = fmaxf(0.f, fmaf(v, s, tt));
}

extern "C" void kernel_launch(void* const* d_in, const int* in_sizes, int n_in,
                              void* d_out, int out_size, void* d_ws, size_t ws_size,
                              hipStream_t stream) {
  const float* x   = (const float*)d_in[0];
  const float* w1  = (const float*)d_in[1];
  const float* b1  = (const float*)d_in[2];
  const float* g1  = (const float*)d_in[3];
  const float* be1 = (const float*)d_in[4];
  const float* w2  = (const float*)d_in[5];
  const float* b2  = (const float*)d_in[6];
  const float* g2  = (const float*)d_in[7];
  const float* be2 = (const float*)d_in[8];
  float* out = (float*)d_out;
  float* ws = (float*)d_ws;

  float* xx   = ws + OFF_XX;
  float* A    = ws + OFF_A;
  float* Cc   = ws + OFF_CC;
  float* ymax = ws + OFF_YMAX;
  float* ymin = ws + OFF_YMIN;
  float* sums = ws + OFF_SUMS;
  float* ST1  = ws + OFF_ST;
  float* ST2  = ST1 + 128;
  int*   idx  = (int*)(ws + OFF_IDX);
  float* xt   = ws + OFF_XT;
  ushort* Phi = (ushort*)(ws + OFF_PHI);
  ushort* Plo = (ushort*)(ws + OFF_PLO);
  ushort* w2p = (ushort*)(ws + OFF_W2P);   // aliases xx (dead after k_knn2)

  hipMemsetAsync(sums, 0, 256 * sizeof(float), stream);

  k_prep  <<<256,  256, 0, stream>>>(x, xx, xt, Phi, Plo);
  k_aw    <<<4096, 256, 0, stream>>>(x, w1, A, Cc);
  k_knn2  <<<512,  512, 0, stream>>>(Phi, Plo, xx, xt, idx);
  k_stats1<<<2560, 256, 0, stream>>>(A, Cc, idx, b1, sums);
  k_fin1  <<<1,    64,  0, stream>>>(sums, b1, g1, be1, w2, ST1, w2p);
  k_l2m   <<<512,  256, 0, stream>>>(A, Cc, idx, ST1, w2p, b2, ymax, ymin, sums + 128);
  k_fin2  <<<1,    64,  0, stream>>>(sums + 128, g2, be2, ST2);
  k_out   <<<4096, 256, 0, stream>>>(ymax, ymin, ST2, out);
}

// Round 5
// 282.244 us; speedup vs baseline: 2.1018x; 1.1438x over previous
//
#include <hip/hip_runtime.h>
#include <float.h>

#define B_ 4
#define C_ 64
#define N_ 4096
#define O_ 64
#define K_ 20
#define EPS_ 1e-5f

typedef float f32x4 __attribute__((ext_vector_type(4)));
typedef short s16x8 __attribute__((ext_vector_type(8)));

union Frag { uint4 u; s16x8 s; };

// ws layout (in float slots)
#define OFF_XX   ((size_t)0)              // 16384 (dead after k_knn3; w2p aliases)
#define OFF_A    ((size_t)16384)          // 1048576
#define OFF_CC   ((size_t)1064960)        // 1048576
#define OFF_YMAX ((size_t)2113536)        // 1048576  (xt lives here until k_l2m)
#define OFF_YMIN ((size_t)3162112)        // 1048576  (Phi+Plo live here until k_l2m)
#define OFF_SUMS ((size_t)4210688)        // 256
#define OFF_ST   ((size_t)4210944)        // 256
#define OFF_IDX  ((size_t)4211200)        // 327680 ints
#define OFF_XT   OFF_YMAX
#define OFF_PHI  OFF_YMIN
#define OFF_PLO  (OFF_YMIN + 524288)
#define OFF_W2P  OFF_XX                   // 8192 ushorts, written by k_fin1

__device__ inline ushort f2bf(float f) {
  uint u = __float_as_uint(f);
  return (ushort)((u + 0x7fffu + ((u >> 16) & 1u)) >> 16);
}
__device__ inline float bf2f(ushort h) { return __uint_as_float(((uint)h) << 16); }

// ------ K0: fused prep: xx, xt, Phi, Plo, A, Cc from one x read ------------
// 256 blocks = (b, 64-point tile), 256 thr = 4 waves (wave w -> 16-pt subtile)
__global__ __launch_bounds__(256) void k_prep(const float* __restrict__ x,
                                              const float* __restrict__ w1,
                                              float* __restrict__ xx,
                                              float* __restrict__ xt,
                                              ushort* __restrict__ Phi,
                                              ushort* __restrict__ Plo,
                                              float* __restrict__ A,
                                              float* __restrict__ Cc) {
  __shared__ float lds[64 * 65];       // x tile [c][n]
  __shared__ ushort ldsW[32 * 512];    // w1a/w1d frags: hi/lo x 2kt x 4ot x 2mat
  const int tid = threadIdx.x;
  const int lane = tid & 63, w = tid >> 6;
  const int b = blockIdx.x >> 6;
  const int n0 = (blockIdx.x & 63) << 6;
  const int bN = b << 12;

  {  // stage x: coalesced
    const int nl = tid & 63;
    const int rbase = (tid >> 6) * 16;
#pragma unroll
    for (int r = 0; r < 16; ++r) {
      int c = rbase + r;
      lds[c * 65 + nl] = x[((size_t)(b * 64 + c)) * N_ + n0 + nl];
    }
  }
  __syncthreads();

  {  // xt[b][n][c]
    int p = tid >> 2, c0 = (tid & 3) << 4;
#pragma unroll
    for (int q = 0; q < 4; ++q) {
      float4 v;
      v.x = lds[(c0 + q * 4 + 0) * 65 + p];
      v.y = lds[(c0 + q * 4 + 1) * 65 + p];
      v.z = lds[(c0 + q * 4 + 2) * 65 + p];
      v.w = lds[(c0 + q * 4 + 3) * 65 + p];
      *(float4*)(xt + ((size_t)(bN + n0 + p)) * 64 + c0 + q * 4) = v;
    }
  }

  // bf16 hi/lo pack of x in MFMA frag order; keep own ptile frags in regs
  Frag xph[2], xpl[2];
  {
    const int nloc = w * 16 + (lane & 15);
    const int gnt = (n0 >> 4) + w;
#pragma unroll
    for (int kt = 0; kt < 2; ++kt) {
      int cbase = kt * 32 + ((lane >> 4) << 3);
      ushort hi[8], lo[8];
#pragma unroll
      for (int e = 0; e < 8; ++e) {
        float v = lds[(cbase + e) * 65 + nloc];
        ushort h = f2bf(v);
        float l = v - bf2f(h);
        hi[e] = h;
        lo[e] = f2bf(l);
      }
      size_t base = ((size_t)((b * 256 + gnt) * 2 + kt)) * 512 + lane * 8;
      uint4 uh, ul;
      uh.x = hi[0] | ((uint)hi[1] << 16); uh.y = hi[2] | ((uint)hi[3] << 16);
      uh.z = hi[4] | ((uint)hi[5] << 16); uh.w = hi[6] | ((uint)hi[7] << 16);
      ul.x = lo[0] | ((uint)lo[1] << 16); ul.y = lo[2] | ((uint)lo[3] << 16);
      ul.z = lo[4] | ((uint)lo[5] << 16); ul.w = lo[6] | ((uint)lo[7] << 16);
      *(uint4*)(Phi + base) = uh;
      *(uint4*)(Plo + base) = ul;
      xph[kt].u = uh;
      xpl[kt].u = ul;
    }
  }

  {  // pack w1a and w1d = w1b - w1a into ldsW frags
    const int l = tid & 63;
    const int sel = tid >> 6, mat = sel & 1, kt = sel >> 1;
#pragma unroll
    for (int ot = 0; ot < 4; ++ot) {
      const int o = ot * 16 + (l & 15);
      uint hw[8], lw[8];
#pragma unroll
      for (int e = 0; e < 8; ++e) {
        int c = kt * 32 + (l >> 4) * 8 + e;
        float wa = w1[o * 128 + c];
        float v = mat ? (w1[o * 128 + 64 + c] - wa) : wa;
        ushort hb = f2bf(v);
        float lv = v - bf2f(hb);
        hw[e] = hb;
        lw[e] = f2bf(lv);
      }
      uint4 uh, ul;
      uh.x = hw[0] | (hw[1] << 16); uh.y = hw[2] | (hw[3] << 16);
      uh.z = hw[4] | (hw[5] << 16); uh.w = hw[6] | (hw[7] << 16);
      ul.x = lw[0] | (lw[1] << 16); ul.y = lw[2] | (lw[3] << 16);
      ul.z = lw[4] | (lw[5] << 16); ul.w = lw[6] | (lw[7] << 16);
      int fb = (mat * 4 + ot) * 4 + kt * 2;
      *(uint4*)(&ldsW[(size_t)(fb + 0) * 512 + l * 8]) = uh;
      *(uint4*)(&ldsW[(size_t)(fb + 1) * 512 + l * 8]) = ul;
    }
  }

  if (tid < 64) {  // xx exact fp32
    float acc = 0.f;
#pragma unroll
    for (int c = 0; c < 64; ++c) {
      float v = lds[c * 65 + tid];
      acc = fmaf(v, v, acc);
    }
    xx[bN + n0 + tid] = acc;
  }
  __syncthreads();

  // MFMA: A = x.w1a^T, Cc = x.w1d^T (3-term bf16 split)
#pragma unroll
  for (int mat = 0; mat < 2; ++mat) {
    float* outp = mat ? Cc : A;
#pragma unroll
    for (int ot = 0; ot < 4; ++ot) {
      int fb = (mat * 4 + ot) * 4;
      Frag bh0, bl0, bh1, bl1;
      bh0.u = *(const uint4*)(&ldsW[(size_t)(fb + 0) * 512 + lane * 8]);
      bl0.u = *(const uint4*)(&ldsW[(size_t)(fb + 1) * 512 + lane * 8]);
      bh1.u = *(const uint4*)(&ldsW[(size_t)(fb + 2) * 512 + lane * 8]);
      bl1.u = *(const uint4*)(&ldsW[(size_t)(fb + 3) * 512 + lane * 8]);
      f32x4 acc = {0.f, 0.f, 0.f, 0.f};
      acc = __builtin_amdgcn_mfma_f32_16x16x32_bf16(xph[0].s, bh0.s, acc, 0, 0, 0);
      acc = __builtin_amdgcn_mfma_f32_16x16x32_bf16(xph[1].s, bh1.s, acc, 0, 0, 0);
      acc = __builtin_amdgcn_mfma_f32_16x16x32_bf16(xph[0].s, bl0.s, acc, 0, 0, 0);
      acc = __builtin_amdgcn_mfma_f32_16x16x32_bf16(xph[1].s, bl1.s, acc, 0, 0, 0);
      acc = __builtin_amdgcn_mfma_f32_16x16x32_bf16(xpl[0].s, bh0.s, acc, 0, 0, 0);
      acc = __builtin_amdgcn_mfma_f32_16x16x32_bf16(xpl[1].s, bh1.s, acc, 0, 0, 0);
#pragma unroll
      for (int r = 0; r < 4; ++r) {
        int ploc = w * 16 + ((lane >> 4) << 2) + r;
        outp[(size_t)(bN + n0 + ploc) * 64 + ot * 16 + (lane & 15)] = acc[r];
      }
    }
  }
}

// ------ K1: kNN (MFMA gram + reg top-2 threshold + exact refine) + BN1 stats
// 1024 blocks: (b, 16-row i-tile). 512 thr = 8 waves, j-stride 8.
__global__ __launch_bounds__(512, 6) void k_knn3(
    const ushort* __restrict__ Phi, const ushort* __restrict__ Plo,
    const float* __restrict__ xx, const float* __restrict__ xt,
    const float* __restrict__ A, const float* __restrict__ Cc,
    const float* __restrict__ b1, int* __restrict__ idxout,
    float* __restrict__ sums) {
  __shared__ float pool[2048];   // 8 KB: [16 rows][128 cell-minima]; reused as red
  __shared__ float xxi[16];
  __shared__ float Tsh[16];
  __shared__ uint  cnt[16];
  __shared__ int   cand[16 * 64];

  const int tid = threadIdx.x;
  const int lane = tid & 63, w = tid >> 6;
  const int b = blockIdx.x >> 8;
  const int i0 = (blockIdx.x & 255) << 4;
  const int bN = b << 12;
  if (tid < 16) { xxi[tid] = xx[bN + i0 + tid]; cnt[tid] = 0; }

  Frag ahi[2], alo[2];
#pragma unroll
  for (int kt = 0; kt < 2; ++kt) {
    size_t off = ((size_t)((b * 256 + (i0 >> 4)) * 2 + kt)) * 512 + lane * 8;
    ahi[kt].u = *(const uint4*)(Phi + off);
    alo[kt].u = *(const uint4*)(Plo + off);
  }
  float xxr[4];
#pragma unroll
  for (int r = 0; r < 4; ++r) xxr[r] = xx[bN + i0 + ((lane >> 4) << 2) + r];

  // ---- pass 0: per-lane top-2 of each owned row-cell (no LDS, no atomics)
  float c1[4], c2[4];
#pragma unroll
  for (int r = 0; r < 4; ++r) { c1[r] = FLT_MAX; c2[r] = FLT_MAX; }
  for (int js = w; js < 256; js += 8) {
    size_t off0 = ((size_t)((b * 256 + js) * 2)) * 512 + lane * 8;
    Frag bh0, bh1, bl0, bl1;
    bh0.u = *(const uint4*)(Phi + off0);
    bh1.u = *(const uint4*)(Phi + off0 + 512);
    bl0.u = *(const uint4*)(Plo + off0);
    bl1.u = *(const uint4*)(Plo + off0 + 512);
    float xxj = xx[bN + js * 16 + (lane & 15)];
    f32x4 acc = {0.f, 0.f, 0.f, 0.f};
    acc = __builtin_amdgcn_mfma_f32_16x16x32_bf16(ahi[0].s, bh0.s, acc, 0, 0, 0);
    acc = __builtin_amdgcn_mfma_f32_16x16x32_bf16(ahi[1].s, bh1.s, acc, 0, 0, 0);
    acc = __builtin_amdgcn_mfma_f32_16x16x32_bf16(ahi[0].s, bl0.s, acc, 0, 0, 0);
    acc = __builtin_amdgcn_mfma_f32_16x16x32_bf16(ahi[1].s, bl1.s, acc, 0, 0, 0);
    acc = __builtin_amdgcn_mfma_f32_16x16x32_bf16(alo[0].s, bh0.s, acc, 0, 0, 0);
    acc = __builtin_amdgcn_mfma_f32_16x16x32_bf16(alo[1].s, bh1.s, acc, 0, 0, 0);
#pragma unroll
    for (int r = 0; r < 4; ++r) {
      float d = fmaf(-2.f, acc[r], xxr[r]) + xxj;
      c2[r] = fminf(c2[r], fmaxf(c1[r], d));
      c1[r] = fminf(c1[r], d);
    }
  }
#pragma unroll
  for (int r = 0; r < 4; ++r)
    pool[(((lane >> 4) << 2) + r) * 128 + w * 16 + (lane & 15)] = c1[r];
  __syncthreads();

  // ---- threshold: 20-round wave min-pop over 128 cell minima (2 rows/wave)
#pragma unroll
  for (int rr = 0; rr < 2; ++rr) {
    const int row = w * 2 + rr;
    float lo = pool[row * 128 + lane];
    float hi = pool[row * 128 + 64 + lane];
    float a = fminf(lo, hi);
    hi = fmaxf(lo, hi);
    lo = a;
    float m = 0.f;
    for (int t = 0; t < 20; ++t) {
      m = lo;
#pragma unroll
      for (int mm = 1; mm < 64; mm <<= 1) m = fminf(m, __shfl_xor(m, mm, 64));
      if (lo == m) { lo = hi; hi = FLT_MAX; }
    }
    if (lane == 0) Tsh[row] = m + 0.5f;   // margin covers bf16-split |err|<=0.25
  }
  __syncthreads();
  float tr[4];
#pragma unroll
  for (int r = 0; r < 4; ++r) tr[r] = Tsh[((lane >> 4) << 2) + r];

  // ---- pass 1: compact candidates (identical deterministic d)
  for (int js = w; js < 256; js += 8) {
    size_t off0 = ((size_t)((b * 256 + js) * 2)) * 512 + lane * 8;
    Frag bh0, bh1, bl0, bl1;
    bh0.u = *(const uint4*)(Phi + off0);
    bh1.u = *(const uint4*)(Phi + off0 + 512);
    bl0.u = *(const uint4*)(Plo + off0);
    bl1.u = *(const uint4*)(Plo + off0 + 512);
    float xxj = xx[bN + js * 16 + (lane & 15)];
    const int jme = js * 16 + (lane & 15);
    f32x4 acc = {0.f, 0.f, 0.f, 0.f};
    acc = __builtin_amdgcn_mfma_f32_16x16x32_bf16(ahi[0].s, bh0.s, acc, 0, 0, 0);
    acc = __builtin_amdgcn_mfma_f32_16x16x32_bf16(ahi[1].s, bh1.s, acc, 0, 0, 0);
    acc = __builtin_amdgcn_mfma_f32_16x16x32_bf16(ahi[0].s, bl0.s, acc, 0, 0, 0);
    acc = __builtin_amdgcn_mfma_f32_16x16x32_bf16(ahi[1].s, bl1.s, acc, 0, 0, 0);
    acc = __builtin_amdgcn_mfma_f32_16x16x32_bf16(alo[0].s, bh0.s, acc, 0, 0, 0);
    acc = __builtin_amdgcn_mfma_f32_16x16x32_bf16(alo[1].s, bh1.s, acc, 0, 0, 0);
#pragma unroll
    for (int r = 0; r < 4; ++r) {
      float d = fmaf(-2.f, acc[r], xxr[r]) + xxj;
      if (d <= tr[r]) {
        int row = ((lane >> 4) << 2) + r;
        uint pos = atomicAdd(&cnt[row], 1u);
        if (pos < 64) cand[row * 64 + pos] = jme;
      }
    }
  }
  __syncthreads();

  // ---- exact refine + bitonic top-20 + fused BN1 stats (2 rows/wave)
  const float b1r = b1[lane];
  float s = 0.f, ssq = 0.f;
  for (int rr = 0; rr < 2; ++rr) {
    const int row = w * 2 + rr;
    const int nc = (int)min(cnt[row], 64u);
    unsigned long long key = ~0ULL;
    if (lane < nc) {
      int j = cand[row * 64 + lane];
      const float* xj = xt + ((size_t)bN + j) * 64;
      const float* xic = xt + ((size_t)bN + i0 + row) * 64;
      float dot = 0.f;
#pragma unroll 8
      for (int c = 0; c < 64; ++c) dot = fmaf(xic[c], xj[c], dot);
      float dex = (xxi[row] - 2.f * dot) + xx[bN + j];
      uint fb = __float_as_uint(dex);
      fb = (fb & 0x80000000u) ? ~fb : (fb | 0x80000000u);
      key = (((unsigned long long)fb) << 32) | (uint)j;
    }
#pragma unroll
    for (int k2 = 2; k2 <= 64; k2 <<= 1) {
#pragma unroll
      for (int mm = k2 >> 1; mm >= 1; mm >>= 1) {
        uint klo = (uint)key, khi = (uint)(key >> 32);
        uint olo = __shfl_xor((int)klo, mm, 64);
        uint ohi = __shfl_xor((int)khi, mm, 64);
        unsigned long long o = (((unsigned long long)ohi) << 32) | olo;
        bool up = ((lane & k2) == 0);
        bool lowhalf = ((lane & mm) == 0);
        bool keepmin = (up == lowhalf);
        key = keepmin ? (key < o ? key : o) : (key > o ? key : o);
      }
    }
    int myj = (int)(uint)key;
    if (lane < 20) idxout[((size_t)bN + i0 + row) * 20 + lane] = myj;

    // BN1 stats for this row's 20 edges: lane = channel
    float ccv = Cc[((size_t)bN + i0 + row) * 64 + lane] + b1r;
#pragma unroll 4
    for (int k = 0; k < 20; ++k) {
      int jk = __shfl(myj, k, 64);
      float av = A[((size_t)bN + jk) * 64 + lane];
      float v = av + ccv;
      s += v;
      ssq = fmaf(v, v, ssq);
    }
  }
  // block reduce (reuse pool) then global atomics
  pool[w * 64 + lane] = s;
  pool[512 + w * 64 + lane] = ssq;
  __syncthreads();
  if (tid < 64) {
    float S = 0.f, Q = 0.f;
#pragma unroll
    for (int q = 0; q < 8; ++q) {
      S += pool[q * 64 + tid];
      Q += pool[512 + q * 64 + tid];
    }
    atomicAdd(&sums[tid], S);
    atomicAdd(&sums[64 + tid], Q);
  }
}

// ---------------- K4: finalize BN1 + pack w2 into MFMA frag order ---------
__global__ void k_fin1(const float* __restrict__ sums, const float* __restrict__ b1,
                       const float* __restrict__ g1, const float* __restrict__ be1,
                       const float* __restrict__ w2, float* __restrict__ ST,
                       ushort* __restrict__ w2p) {
  int o = threadIdx.x;   // 0..63
  const float E = 327680.f;
  float m = sums[o] / E;
  float var = fmaxf(sums[64 + o] / E - m * m, 0.f);
  float s = g1[o] / sqrtf(var + EPS_);
  ST[o] = s;
  ST[64 + o] = be1[o] + (b1[o] - m) * s;

  const int colp = o & 15, gp = o >> 4;
#pragma unroll
  for (int ot = 0; ot < 4; ++ot) {
#pragma unroll
    for (int kt = 0; kt < 2; ++kt) {
      uint hw[8], lw[8];
#pragma unroll
      for (int e = 0; e < 8; ++e) {
        float v = w2[(ot * 16 + colp) * 64 + kt * 32 + gp * 8 + e];
        ushort hb = f2bf(v);
        float lv = v - bf2f(hb);
        hw[e] = hb;
        lw[e] = f2bf(lv);
      }
      uint4 uh, ul;
      uh.x = hw[0] | (hw[1] << 16); uh.y = hw[2] | (hw[3] << 16);
      uh.z = hw[4] | (hw[5] << 16); uh.w = hw[6] | (hw[7] << 16);
      ul.x = lw[0] | (lw[1] << 16); ul.y = lw[2] | (lw[3] << 16);
      ul.z = lw[4] | (lw[5] << 16); ul.w = lw[6] | (lw[7] << 16);
      int f = (ot * 2 + kt) * 2;
      *(uint4*)(w2p + (size_t)f * 512 + o * 8) = uh;
      *(uint4*)(w2p + (size_t)(f + 1) * 512 + o * 8) = ul;
    }
  }
}

// ---------------- K5: MFMA layer-2 + BN2 stats + per-point max/min --------
// 1024 blocks x 256 thr (4 waves); wave handles 4 points.
__global__ __launch_bounds__(256, 2) void k_l2m(
    const float* __restrict__ A, const float* __restrict__ Cc,
    const int* __restrict__ idx, const float* __restrict__ ST1,
    const ushort* __restrict__ w2p, const float* __restrict__ b2,
    float* __restrict__ ymax, float* __restrict__ ymin,
    float* __restrict__ sums2) {
  const int tid = threadIdx.x;
  const int lane = tid & 63, w = tid >> 6;
  const int g = lane >> 4, col = lane & 15;

  Frag wh[4][2], wl[4][2];
#pragma unroll
  for (int ot = 0; ot < 4; ++ot)
#pragma unroll
    for (int kt = 0; kt < 2; ++kt) {
      int f = (ot * 2 + kt) * 2;
      wh[ot][kt].u = *(const uint4*)(w2p + (size_t)f * 512 + lane * 8);
      wl[ot][kt].u = *(const uint4*)(w2p + (size_t)(f + 1) * 512 + lane * 8);
    }

  float S1v[2][8], T1v[2][8];
#pragma unroll
  for (int kt = 0; kt < 2; ++kt) {
    int c0 = kt * 32 + g * 8;
    *(float4*)&S1v[kt][0] = *(const float4*)(ST1 + c0);
    *(float4*)&S1v[kt][4] = *(const float4*)(ST1 + c0 + 4);
    *(float4*)&T1v[kt][0] = *(const float4*)(ST1 + 64 + c0);
    *(float4*)&T1v[kt][4] = *(const float4*)(ST1 + 64 + c0 + 4);
  }
  float b2r[4];
#pragma unroll
  for (int ot = 0; ot < 4; ++ot) b2r[ot] = b2[ot * 16 + col];

  float ps[4] = {0.f, 0.f, 0.f, 0.f}, pss[4] = {0.f, 0.f, 0.f, 0.f};

  for (int it = 0; it < 4; ++it) {
    const int p = (blockIdx.x * 4 + w) * 4 + it;
    const int bbase = (p >> 12) << 12;
    const float* Cp = Cc + (size_t)p * 64;
    float mx[4], mn[4];
#pragma unroll
    for (int ot = 0; ot < 4; ++ot) { mx[ot] = -FLT_MAX; mn[ot] = FLT_MAX; }

#pragma unroll
    for (int t = 0; t < 2; ++t) {
      int kk = t * 16 + col;
      kk = kk > 19 ? 19 : kk;
      int j = idx[p * 20 + kk];
      const float* Ap = A + ((size_t)(bbase + j)) * 64;
      Frag hh[2];
#pragma unroll
      for (int kt = 0; kt < 2; ++kt) {
        int c0 = kt * 32 + g * 8;
        float4 a0 = *(const float4*)(Ap + c0);
        float4 a1 = *(const float4*)(Ap + c0 + 4);
        float4 q0 = *(const float4*)(Cp + c0);
        float4 q1 = *(const float4*)(Cp + c0 + 4);
        float hv[8];
        hv[0] = fmaxf(0.f, fmaf(a0.x + q0.x, S1v[kt][0], T1v[kt][0]));
        hv[1] = fmaxf(0.f, fmaf(a0.y + q0.y, S1v[kt][1], T1v[kt][1]));
        hv[2] = fmaxf(0.f, fmaf(a0.z + q0.z, S1v[kt][2], T1v[kt][2]));
        hv[3] = fmaxf(0.f, fmaf(a0.w + q0.w, S1v[kt][3], T1v[kt][3]));
        hv[4] = fmaxf(0.f, fmaf(a1.x + q1.x, S1v[kt][4], T1v[kt][4]));
        hv[5] = fmaxf(0.f, fmaf(a1.y + q1.y, S1v[kt][5], T1v[kt][5]));
        hv[6] = fmaxf(0.f, fmaf(a1.z + q1.z, S1v[kt][6], T1v[kt][6]));
        hv[7] = fmaxf(0.f, fmaf(a1.w + q1.w, S1v[kt][7], T1v[kt][7]));
        uint4 uh;
        uh.x = f2bf(hv[0]) | ((uint)f2bf(hv[1]) << 16);
        uh.y = f2bf(hv[2]) | ((uint)f2bf(hv[3]) << 16);
        uh.z = f2bf(hv[4]) | ((uint)f2bf(hv[5]) << 16);
        uh.w = f2bf(hv[6]) | ((uint)f2bf(hv[7]) << 16);
        hh[kt].u = uh;
      }
#pragma unroll
      for (int ot = 0; ot < 4; ++ot) {
        f32x4 acc = {0.f, 0.f, 0.f, 0.f};
        acc = __builtin_amdgcn_mfma_f32_16x16x32_bf16(hh[0].s, wh[ot][0].s, acc, 0, 0, 0);
        acc = __builtin_amdgcn_mfma_f32_16x16x32_bf16(hh[1].s, wh[ot][1].s, acc, 0, 0, 0);
        acc = __builtin_amdgcn_mfma_f32_16x16x32_bf16(hh[0].s, wl[ot][0].s, acc, 0, 0, 0);
        acc = __builtin_amdgcn_mfma_f32_16x16x32_bf16(hh[1].s, wl[ot][1].s, acc, 0, 0, 0);
        if (t == 0) {
#pragma unroll
          for (int r = 0; r < 4; ++r) {
            float y = acc[r] + b2r[ot];
            mx[ot] = fmaxf(mx[ot], y);
            mn[ot] = fminf(mn[ot], y);
            ps[ot] += y;
            pss[ot] = fmaf(y, y, pss[ot]);
          }
        } else if (g == 0) {
#pragma unroll
          for (int r = 0; r < 4; ++r) {
            float y = acc[r] + b2r[ot];
            mx[ot] = fmaxf(mx[ot], y);
            mn[ot] = fminf(mn[ot], y);
            ps[ot] += y;
            pss[ot] = fmaf(y, y, pss[ot]);
          }
        }
      }
    }

#pragma unroll
    for (int ot = 0; ot < 4; ++ot) {
      float v = mx[ot];
      v = fmaxf(v, __shfl_xor(v, 16, 64));
      v = fmaxf(v, __shfl_xor(v, 32, 64));
      mx[ot] = v;
      float u = mn[ot];
      u = fminf(u, __shfl_xor(u, 16, 64));
      u = fminf(u, __shfl_xor(u, 32, 64));
      mn[ot] = u;
    }
    float wmx = mx[0], wmn = mn[0];
    if (g == 1) { wmx = mx[1]; wmn = mn[1]; }
    if (g == 2) { wmx = mx[2]; wmn = mn[2]; }
    if (g == 3) { wmx = mx[3]; wmn = mn[3]; }
    ymax[(size_t)p * 64 + lane] = wmx;
    ymin[(size_t)p * 64 + lane] = wmn;
  }

#pragma unroll
  for (int ot = 0; ot < 4; ++ot) {
    float s = ps[ot];
    s += __shfl_xor(s, 16, 64);
    s += __shfl_xor(s, 32, 64);
    float q = pss[ot];
    q += __shfl_xor(q, 16, 64);
    q += __shfl_xor(q, 32, 64);
    if (g == ot) {
      atomicAdd(&sums2[ot * 16 + col], s);
      atomicAdd(&sums2[64 + ot * 16 + col], q);
    }
  }
}

// ---------------- K6a: finalize BN2 ----------------
__global__ void k_fin2(const float* __restrict__ sums2, const float* __restrict__ g2,
                       const float* __restrict__ be2, float* __restrict__ ST2) {
  int o = threadIdx.x;
  const float E = 327680.f;
  float m = sums2[o] / E;
  float var = fmaxf(sums2[64 + o] / E - m * m, 0.f);
  float s = g2[o] / sqrtf(var + EPS_);
  ST2[o] = s;
  ST2[64 + o] = be2[o] - m * s;
}

// ---------------- K6b: epilogue out[b][o][n] ----------------
__global__ __launch_bounds__(256) void k_out(const float* __restrict__ ymax,
                                             const float* __restrict__ ymin,
                                             const float* __restrict__ ST2,
                                             float* __restrict__ out) {
  int t = blockIdx.x * 256 + threadIdx.x;
  int n = t & 4095;
  int o = (t >> 12) & 63;
  int b = t >> 18;
  float s = ST2[o], tt = ST2[64 + o];
  size_t p = ((size_t)b << 12) + n;
  float v = (s >= 0.f) ? ymax[p * 64 + o] : ymin[p * 64 + o];
  out[t] = fmaxf(0.f, fmaf(v, s, tt));
}

extern "C" void kernel_launch(void* const* d_in, const int* in_sizes, int n_in,
                              void* d_out, int out_size, void* d_ws, size_t ws_size,
                              hipStream_t stream) {
  const float* x   = (const float*)d_in[0];
  const float* w1  = (const float*)d_in[1];
  const float* b1  = (const float*)d_in[2];
  const float* g1  = (const float*)d_in[3];
  const float* be1 = (const float*)d_in[4];
  const float* w2  = (const float*)d_in[5];
  const float* b2  = (const float*)d_in[6];
  const float* g2  = (const float*)d_in[7];
  const float* be2 = (const float*)d_in[8];
  float* out = (float*)d_out;
  float* ws = (float*)d_ws;

  float* xx   = ws + OFF_XX;
  float* A    = ws + OFF_A;
  float* Cc   = ws + OFF_CC;
  float* ymax = ws + OFF_YMAX;
  float* ymin = ws + OFF_YMIN;
  float* sums = ws + OFF_SUMS;
  float* ST1  = ws + OFF_ST;
  float* ST2  = ST1 + 128;
  int*   idx  = (int*)(ws + OFF_IDX);
  float* xt   = ws + OFF_XT;
  ushort* Phi = (ushort*)(ws + OFF_PHI);
  ushort* Plo = (ushort*)(ws + OFF_PLO);
  ushort* w2p = (ushort*)(ws + OFF_W2P);

  hipMemsetAsync(sums, 0, 256 * sizeof(float), stream);

  k_prep <<<256,  256, 0, stream>>>(x, w1, xx, xt, Phi, Plo, A, Cc);
  k_knn3 <<<1024, 512, 0, stream>>>(Phi, Plo, xx, xt, A, Cc, b1, idx, sums);
  k_fin1 <<<1,    64,  0, stream>>>(sums, b1, g1, be1, w2, ST1, w2p);
  k_l2m  <<<1024, 256, 0, stream>>>(A, Cc, idx, ST1, w2p, b2, ymax, ymin, sums + 128);
  k_fin2 <<<1,    64,  0, stream>>>(sums + 128, g2, be2, ST2);
  k_out  <<<4096, 256, 0, stream>>>(ymax, ymin, ST2, out);
}

// Round 6
// 202.333 us; speedup vs baseline: 2.9319x; 1.3949x over previous
//
#include <hip/hip_runtime.h>
#include <float.h>

#define B_ 4
#define C_ 64
#define N_ 4096
#define O_ 64
#define K_ 20
#define EPS_ 1e-5f

typedef float f32x4 __attribute__((ext_vector_type(4)));
typedef short s16x8 __attribute__((ext_vector_type(8)));

union Frag { uint4 u; s16x8 s; };

// ws layout (in float slots)
#define OFF_XX   ((size_t)0)              // 16384 (dead after k_knn4; w2p aliases)
#define OFF_A    ((size_t)16384)          // 1048576
#define OFF_CC   ((size_t)1064960)        // 1048576
#define OFF_YMAX ((size_t)2113536)        // 1048576  (xt lives here until k_l2m2)
#define OFF_YMIN ((size_t)3162112)        // 1048576  (Phi+Plo live here until k_l2m2)
#define OFF_SUMS ((size_t)4210688)        // 256
#define OFF_ST   ((size_t)4210944)        // 256
#define OFF_IDX  ((size_t)4211200)        // 327680 ints
#define OFF_XT   OFF_YMAX
#define OFF_PHI  OFF_YMIN
#define OFF_PLO  (OFF_YMIN + 524288)
#define OFF_W2P  OFF_XX

__device__ inline ushort f2bf(float f) {
  uint u = __float_as_uint(f);
  return (ushort)((u + 0x7fffu + ((u >> 16) & 1u)) >> 16);
}
__device__ inline float bf2f(ushort h) { return __uint_as_float(((uint)h) << 16); }

// ------ K0: fused prep: xx, xt, Phi, Plo, A, Cc from one x read ------------
__global__ __launch_bounds__(256) void k_prep(const float* __restrict__ x,
                                              const float* __restrict__ w1,
                                              float* __restrict__ xx,
                                              float* __restrict__ xt,
                                              ushort* __restrict__ Phi,
                                              ushort* __restrict__ Plo,
                                              float* __restrict__ A,
                                              float* __restrict__ Cc) {
  __shared__ float lds[64 * 65];
  __shared__ ushort ldsW[32 * 512];
  const int tid = threadIdx.x;
  const int lane = tid & 63, w = tid >> 6;
  const int b = blockIdx.x >> 6;
  const int n0 = (blockIdx.x & 63) << 6;
  const int bN = b << 12;

  {
    const int nl = tid & 63;
    const int rbase = (tid >> 6) * 16;
#pragma unroll
    for (int r = 0; r < 16; ++r) {
      int c = rbase + r;
      lds[c * 65 + nl] = x[((size_t)(b * 64 + c)) * N_ + n0 + nl];
    }
  }
  __syncthreads();

  {
    int p = tid >> 2, c0 = (tid & 3) << 4;
#pragma unroll
    for (int q = 0; q < 4; ++q) {
      float4 v;
      v.x = lds[(c0 + q * 4 + 0) * 65 + p];
      v.y = lds[(c0 + q * 4 + 1) * 65 + p];
      v.z = lds[(c0 + q * 4 + 2) * 65 + p];
      v.w = lds[(c0 + q * 4 + 3) * 65 + p];
      *(float4*)(xt + ((size_t)(bN + n0 + p)) * 64 + c0 + q * 4) = v;
    }
  }

  Frag xph[2], xpl[2];
  {
    const int nloc = w * 16 + (lane & 15);
    const int gnt = (n0 >> 4) + w;
#pragma unroll
    for (int kt = 0; kt < 2; ++kt) {
      int cbase = kt * 32 + ((lane >> 4) << 3);
      ushort hi[8], lo[8];
#pragma unroll
      for (int e = 0; e < 8; ++e) {
        float v = lds[(cbase + e) * 65 + nloc];
        ushort h = f2bf(v);
        float l = v - bf2f(h);
        hi[e] = h;
        lo[e] = f2bf(l);
      }
      size_t base = ((size_t)((b * 256 + gnt) * 2 + kt)) * 512 + lane * 8;
      uint4 uh, ul;
      uh.x = hi[0] | ((uint)hi[1] << 16); uh.y = hi[2] | ((uint)hi[3] << 16);
      uh.z = hi[4] | ((uint)hi[5] << 16); uh.w = hi[6] | ((uint)hi[7] << 16);
      ul.x = lo[0] | ((uint)lo[1] << 16); ul.y = lo[2] | ((uint)lo[3] << 16);
      ul.z = lo[4] | ((uint)lo[5] << 16); ul.w = lo[6] | ((uint)lo[7] << 16);
      *(uint4*)(Phi + base) = uh;
      *(uint4*)(Plo + base) = ul;
      xph[kt].u = uh;
      xpl[kt].u = ul;
    }
  }

  {
    const int l = tid & 63;
    const int sel = tid >> 6, mat = sel & 1, kt = sel >> 1;
#pragma unroll
    for (int ot = 0; ot < 4; ++ot) {
      const int o = ot * 16 + (l & 15);
      uint hw[8], lw[8];
#pragma unroll
      for (int e = 0; e < 8; ++e) {
        int c = kt * 32 + (l >> 4) * 8 + e;
        float wa = w1[o * 128 + c];
        float v = mat ? (w1[o * 128 + 64 + c] - wa) : wa;
        ushort hb = f2bf(v);
        float lv = v - bf2f(hb);
        hw[e] = hb;
        lw[e] = f2bf(lv);
      }
      uint4 uh, ul;
      uh.x = hw[0] | (hw[1] << 16); uh.y = hw[2] | (hw[3] << 16);
      uh.z = hw[4] | (hw[5] << 16); uh.w = hw[6] | (hw[7] << 16);
      ul.x = lw[0] | (lw[1] << 16); ul.y = lw[2] | (lw[3] << 16);
      ul.z = lw[4] | (lw[5] << 16); ul.w = lw[6] | (lw[7] << 16);
      int fb = (mat * 4 + ot) * 4 + kt * 2;
      *(uint4*)(&ldsW[(size_t)(fb + 0) * 512 + l * 8]) = uh;
      *(uint4*)(&ldsW[(size_t)(fb + 1) * 512 + l * 8]) = ul;
    }
  }

  if (tid < 64) {
    float acc = 0.f;
#pragma unroll
    for (int c = 0; c < 64; ++c) {
      float v = lds[c * 65 + tid];
      acc = fmaf(v, v, acc);
    }
    xx[bN + n0 + tid] = acc;
  }
  __syncthreads();

#pragma unroll
  for (int mat = 0; mat < 2; ++mat) {
    float* outp = mat ? Cc : A;
#pragma unroll
    for (int ot = 0; ot < 4; ++ot) {
      int fb = (mat * 4 + ot) * 4;
      Frag bh0, bl0, bh1, bl1;
      bh0.u = *(const uint4*)(&ldsW[(size_t)(fb + 0) * 512 + lane * 8]);
      bl0.u = *(const uint4*)(&ldsW[(size_t)(fb + 1) * 512 + lane * 8]);
      bh1.u = *(const uint4*)(&ldsW[(size_t)(fb + 2) * 512 + lane * 8]);
      bl1.u = *(const uint4*)(&ldsW[(size_t)(fb + 3) * 512 + lane * 8]);
      f32x4 acc = {0.f, 0.f, 0.f, 0.f};
      acc = __builtin_amdgcn_mfma_f32_16x16x32_bf16(xph[0].s, bh0.s, acc, 0, 0, 0);
      acc = __builtin_amdgcn_mfma_f32_16x16x32_bf16(xph[1].s, bh1.s, acc, 0, 0, 0);
      acc = __builtin_amdgcn_mfma_f32_16x16x32_bf16(xph[0].s, bl0.s, acc, 0, 0, 0);
      acc = __builtin_amdgcn_mfma_f32_16x16x32_bf16(xph[1].s, bl1.s, acc, 0, 0, 0);
      acc = __builtin_amdgcn_mfma_f32_16x16x32_bf16(xpl[0].s, bh0.s, acc, 0, 0, 0);
      acc = __builtin_amdgcn_mfma_f32_16x16x32_bf16(xpl[1].s, bh1.s, acc, 0, 0, 0);
#pragma unroll
      for (int r = 0; r < 4; ++r) {
        int ploc = w * 16 + ((lane >> 4) << 2) + r;
        outp[(size_t)(bN + n0 + ploc) * 64 + ot * 16 + (lane & 15)] = acc[r];
      }
    }
  }
}

// ------ K1: kNN, 32-row tiles, dbuf loads, reg-min threshold, exact refine,
//        fused BN1 stats. 512 blocks x 512 thr (8 waves, j-stride 8).
__global__ __launch_bounds__(512, 2) void k_knn4(
    const ushort* __restrict__ Phi, const ushort* __restrict__ Plo,
    const float* __restrict__ xx, const float* __restrict__ xt,
    const float* __restrict__ A, const float* __restrict__ Cc,
    const float* __restrict__ b1, int* __restrict__ idxout,
    float* __restrict__ sums) {
  __shared__ float pool[4096];   // 16 KB: [32 rows][128 cell minima]; reused
  __shared__ float xxi[32];
  __shared__ float Tsh[32];
  __shared__ uint  cnt[32];
  __shared__ int   cand[32 * 64];  // 8 KB

  const int tid = threadIdx.x;
  const int lane = tid & 63, w = tid >> 6;
  const int col = lane & 15, g4 = (lane >> 4) << 2;
  const int b = blockIdx.x >> 7;
  const int i0 = (blockIdx.x & 127) << 5;
  const int bN = b << 12;
  if (tid < 32) { xxi[tid] = xx[bN + i0 + tid]; cnt[tid] = 0; }

  Frag ahi[2][2], alo[2][2];
#pragma unroll
  for (int isub = 0; isub < 2; ++isub) {
    int nt = (i0 >> 4) + isub;
#pragma unroll
    for (int kt = 0; kt < 2; ++kt) {
      size_t off = ((size_t)((b * 256 + nt) * 2 + kt)) * 512 + lane * 8;
      ahi[isub][kt].u = *(const uint4*)(Phi + off);
      alo[isub][kt].u = *(const uint4*)(Plo + off);
    }
  }
  float xxr[8];
#pragma unroll
  for (int isub = 0; isub < 2; ++isub)
#pragma unroll
    for (int r = 0; r < 4; ++r)
      xxr[isub * 4 + r] = xx[bN + i0 + isub * 16 + g4 + r];

  struct BTile { Frag h0, h1, l0, l1; float xxj; };
  auto loadB = [&](int js, BTile& t) {
    size_t off0 = ((size_t)((b * 256 + js) * 2)) * 512 + lane * 8;
    t.h0.u = *(const uint4*)(Phi + off0);
    t.h1.u = *(const uint4*)(Phi + off0 + 512);
    t.l0.u = *(const uint4*)(Plo + off0);
    t.l1.u = *(const uint4*)(Plo + off0 + 512);
    t.xxj = xx[bN + js * 16 + col];
  };

  float c1[8];
#pragma unroll
  for (int r = 0; r < 8; ++r) c1[r] = FLT_MAX;

  auto top2 = [&](const BTile& t) {
#pragma unroll
    for (int isub = 0; isub < 2; ++isub) {
      f32x4 acc = {0.f, 0.f, 0.f, 0.f};
      acc = __builtin_amdgcn_mfma_f32_16x16x32_bf16(ahi[isub][0].s, t.h0.s, acc, 0, 0, 0);
      acc = __builtin_amdgcn_mfma_f32_16x16x32_bf16(ahi[isub][1].s, t.h1.s, acc, 0, 0, 0);
      acc = __builtin_amdgcn_mfma_f32_16x16x32_bf16(ahi[isub][0].s, t.l0.s, acc, 0, 0, 0);
      acc = __builtin_amdgcn_mfma_f32_16x16x32_bf16(ahi[isub][1].s, t.l1.s, acc, 0, 0, 0);
      acc = __builtin_amdgcn_mfma_f32_16x16x32_bf16(alo[isub][0].s, t.h0.s, acc, 0, 0, 0);
      acc = __builtin_amdgcn_mfma_f32_16x16x32_bf16(alo[isub][1].s, t.h1.s, acc, 0, 0, 0);
#pragma unroll
      for (int r = 0; r < 4; ++r) {
        float d = fmaf(-2.f, acc[r], xxr[isub * 4 + r]) + t.xxj;
        c1[isub * 4 + r] = fminf(c1[isub * 4 + r], d);
      }
    }
  };

  {
    BTile t0, t1;
    loadB(w, t0);
    for (int js = w; js < 256; js += 16) {
      loadB(js + 8, t1);
      top2(t0);
      if (js + 16 < 256) loadB(js + 16, t0);
      top2(t1);
    }
  }
#pragma unroll
  for (int isub = 0; isub < 2; ++isub)
#pragma unroll
    for (int r = 0; r < 4; ++r)
      pool[(isub * 16 + g4 + r) * 128 + w * 16 + col] = c1[isub * 4 + r];
  __syncthreads();

  // threshold: 20-round min-pop over 128 cell minima (4 rows/wave)
#pragma unroll
  for (int rr = 0; rr < 4; ++rr) {
    const int row = w * 4 + rr;
    float lo = pool[row * 128 + lane];
    float hi = pool[row * 128 + 64 + lane];
    float a = fminf(lo, hi);
    hi = fmaxf(lo, hi);
    lo = a;
    float m = 0.f;
    for (int t = 0; t < 20; ++t) {
      m = lo;
#pragma unroll
      for (int mm = 1; mm < 64; mm <<= 1) m = fminf(m, __shfl_xor(m, mm, 64));
      if (lo == m) { lo = hi; hi = FLT_MAX; }
    }
    if (lane == 0) Tsh[row] = m + 0.5f;   // covers bf16-split |err| <= 0.25
  }
  __syncthreads();
  float tr[8];
#pragma unroll
  for (int isub = 0; isub < 2; ++isub)
#pragma unroll
    for (int r = 0; r < 4; ++r) tr[isub * 4 + r] = Tsh[isub * 16 + g4 + r];

  auto passc = [&](int js, const BTile& t) {
    const int jme = js * 16 + col;
#pragma unroll
    for (int isub = 0; isub < 2; ++isub) {
      f32x4 acc = {0.f, 0.f, 0.f, 0.f};
      acc = __builtin_amdgcn_mfma_f32_16x16x32_bf16(ahi[isub][0].s, t.h0.s, acc, 0, 0, 0);
      acc = __builtin_amdgcn_mfma_f32_16x16x32_bf16(ahi[isub][1].s, t.h1.s, acc, 0, 0, 0);
      acc = __builtin_amdgcn_mfma_f32_16x16x32_bf16(ahi[isub][0].s, t.l0.s, acc, 0, 0, 0);
      acc = __builtin_amdgcn_mfma_f32_16x16x32_bf16(ahi[isub][1].s, t.l1.s, acc, 0, 0, 0);
      acc = __builtin_amdgcn_mfma_f32_16x16x32_bf16(alo[isub][0].s, t.h0.s, acc, 0, 0, 0);
      acc = __builtin_amdgcn_mfma_f32_16x16x32_bf16(alo[isub][1].s, t.h1.s, acc, 0, 0, 0);
#pragma unroll
      for (int r = 0; r < 4; ++r) {
        float d = fmaf(-2.f, acc[r], xxr[isub * 4 + r]) + t.xxj;
        if (d <= tr[isub * 4 + r]) {
          int row = isub * 16 + g4 + r;
          uint pos = atomicAdd(&cnt[row], 1u);
          if (pos < 64) cand[row * 64 + pos] = jme;
        }
      }
    }
  };

  {
    BTile t0, t1;
    loadB(w, t0);
    for (int js = w; js < 256; js += 16) {
      loadB(js + 8, t1);
      passc(js, t0);
      if (js + 16 < 256) loadB(js + 16, t0);
      passc(js + 8, t1);
    }
  }
  __syncthreads();

  // exact refine + bitonic top-20 + fused BN1 stats (4 rows/wave)
  const float b1r = b1[lane];
  float s = 0.f, ssq = 0.f;
  for (int rr = 0; rr < 4; ++rr) {
    const int row = w * 4 + rr;
    const int nc = (int)min(cnt[row], 64u);
    unsigned long long key = ~0ULL;
    if (lane < nc) {
      int j = cand[row * 64 + lane];
      const float* xj = xt + ((size_t)bN + j) * 64;
      const float* xic = xt + ((size_t)bN + i0 + row) * 64;
      float dot = 0.f;
#pragma unroll 8
      for (int c = 0; c < 64; ++c) dot = fmaf(xic[c], xj[c], dot);
      float dex = (xxi[row] - 2.f * dot) + xx[bN + j];
      uint fb = __float_as_uint(dex);
      fb = (fb & 0x80000000u) ? ~fb : (fb | 0x80000000u);
      key = (((unsigned long long)fb) << 32) | (uint)j;
    }
#pragma unroll
    for (int k2 = 2; k2 <= 64; k2 <<= 1) {
#pragma unroll
      for (int mm = k2 >> 1; mm >= 1; mm >>= 1) {
        uint klo = (uint)key, khi = (uint)(key >> 32);
        uint olo = __shfl_xor((int)klo, mm, 64);
        uint ohi = __shfl_xor((int)khi, mm, 64);
        unsigned long long o = (((unsigned long long)ohi) << 32) | olo;
        bool up = ((lane & k2) == 0);
        bool lowhalf = ((lane & mm) == 0);
        bool keepmin = (up == lowhalf);
        key = keepmin ? (key < o ? key : o) : (key > o ? key : o);
      }
    }
    int myj = (int)(uint)key;
    if (lane < 20) idxout[((size_t)bN + i0 + row) * 20 + lane] = myj;

    float ccv = Cc[((size_t)bN + i0 + row) * 64 + lane] + b1r;
#pragma unroll 4
    for (int k = 0; k < 20; ++k) {
      int jk = __shfl(myj, k, 64);
      float av = A[((size_t)bN + jk) * 64 + lane];
      float v = av + ccv;
      s += v;
      ssq = fmaf(v, v, ssq);
    }
  }
  __syncthreads();        // pool (cell minima) dead; reuse for reduction
  pool[w * 64 + lane] = s;
  pool[512 + w * 64 + lane] = ssq;
  __syncthreads();
  if (tid < 64) {
    float S = 0.f, Q = 0.f;
#pragma unroll
    for (int q = 0; q < 8; ++q) {
      S += pool[q * 64 + tid];
      Q += pool[512 + q * 64 + tid];
    }
    atomicAdd(&sums[tid], S);
    atomicAdd(&sums[64 + tid], Q);
  }
}

// ---------------- K4: finalize BN1 + pack w2 into MFMA frag order ---------
__global__ void k_fin1(const float* __restrict__ sums, const float* __restrict__ b1,
                       const float* __restrict__ g1, const float* __restrict__ be1,
                       const float* __restrict__ w2, float* __restrict__ ST,
                       ushort* __restrict__ w2p) {
  int o = threadIdx.x;
  const float E = 327680.f;
  float m = sums[o] / E;
  float var = fmaxf(sums[64 + o] / E - m * m, 0.f);
  float s = g1[o] / sqrtf(var + EPS_);
  ST[o] = s;
  ST[64 + o] = be1[o] + (b1[o] - m) * s;

  const int colp = o & 15, gp = o >> 4;
#pragma unroll
  for (int ot = 0; ot < 4; ++ot) {
#pragma unroll
    for (int kt = 0; kt < 2; ++kt) {
      uint hw[8], lw[8];
#pragma unroll
      for (int e = 0; e < 8; ++e) {
        float v = w2[(ot * 16 + colp) * 64 + kt * 32 + gp * 8 + e];
        ushort hb = f2bf(v);
        float lv = v - bf2f(hb);
        hw[e] = hb;
        lw[e] = f2bf(lv);
      }
      uint4 uh, ul;
      uh.x = hw[0] | (hw[1] << 16); uh.y = hw[2] | (hw[3] << 16);
      uh.z = hw[4] | (hw[5] << 16); uh.w = hw[6] | (hw[7] << 16);
      ul.x = lw[0] | (lw[1] << 16); ul.y = lw[2] | (lw[3] << 16);
      ul.z = lw[4] | (lw[5] << 16); ul.w = lw[6] | (lw[7] << 16);
      int f = (ot * 2 + kt) * 2;
      *(uint4*)(w2p + (size_t)f * 512 + o * 8) = uh;
      *(uint4*)(w2p + (size_t)(f + 1) * 512 + o * 8) = ul;
    }
  }
}

// ------ K5: MFMA layer-2, 2 points in flight per wave. 2048 blocks x 256 thr.
__global__ __launch_bounds__(256, 2) void k_l2m2(
    const float* __restrict__ A, const float* __restrict__ Cc,
    const int* __restrict__ idx, const float* __restrict__ ST1,
    const ushort* __restrict__ w2p, const float* __restrict__ b2,
    float* __restrict__ ymax, float* __restrict__ ymin,
    float* __restrict__ sums2) {
  __shared__ float red2[512];
  const int tid = threadIdx.x;
  const int lane = tid & 63, w = tid >> 6;
  const int g = lane >> 4, col = lane & 15;

  Frag wh[4][2], wl[4][2];
#pragma unroll
  for (int ot = 0; ot < 4; ++ot)
#pragma unroll
    for (int kt = 0; kt < 2; ++kt) {
      int f = (ot * 2 + kt) * 2;
      wh[ot][kt].u = *(const uint4*)(w2p + (size_t)f * 512 + lane * 8);
      wl[ot][kt].u = *(const uint4*)(w2p + (size_t)(f + 1) * 512 + lane * 8);
    }

  float S1v[2][8], T1v[2][8];
#pragma unroll
  for (int kt = 0; kt < 2; ++kt) {
    int c0 = kt * 32 + g * 8;
    *(float4*)&S1v[kt][0] = *(const float4*)(ST1 + c0);
    *(float4*)&S1v[kt][4] = *(const float4*)(ST1 + c0 + 4);
    *(float4*)&T1v[kt][0] = *(const float4*)(ST1 + 64 + c0);
    *(float4*)&T1v[kt][4] = *(const float4*)(ST1 + 64 + c0 + 4);
  }
  float b2r[4];
#pragma unroll
  for (int ot = 0; ot < 4; ++ot) b2r[ot] = b2[ot * 16 + col];

  const int p0 = (blockIdx.x * 4 + w) * 2;
  const int bbase = (p0 >> 12) << 12;

  // build all 8 h-fragments (2 pts x 2 ktiles x 2 kt) -- independent chains
  Frag hh[2][2][2];
#pragma unroll
  for (int pt = 0; pt < 2; ++pt) {
    const int p = p0 + pt;
    const float* Cp = Cc + (size_t)p * 64;
#pragma unroll
    for (int t = 0; t < 2; ++t) {
      int kk = t * 16 + col;
      kk = kk > 19 ? 19 : kk;
      int j = idx[p * 20 + kk];
      const float* Ap = A + ((size_t)(bbase + j)) * 64;
#pragma unroll
      for (int kt = 0; kt < 2; ++kt) {
        int c0 = kt * 32 + g * 8;
        float4 a0 = *(const float4*)(Ap + c0);
        float4 a1 = *(const float4*)(Ap + c0 + 4);
        float4 q0 = *(const float4*)(Cp + c0);
        float4 q1 = *(const float4*)(Cp + c0 + 4);
        float hv[8];
        hv[0] = fmaxf(0.f, fmaf(a0.x + q0.x, S1v[kt][0], T1v[kt][0]));
        hv[1] = fmaxf(0.f, fmaf(a0.y + q0.y, S1v[kt][1], T1v[kt][1]));
        hv[2] = fmaxf(0.f, fmaf(a0.z + q0.z, S1v[kt][2], T1v[kt][2]));
        hv[3] = fmaxf(0.f, fmaf(a0.w + q0.w, S1v[kt][3], T1v[kt][3]));
        hv[4] = fmaxf(0.f, fmaf(a1.x + q1.x, S1v[kt][4], T1v[kt][4]));
        hv[5] = fmaxf(0.f, fmaf(a1.y + q1.y, S1v[kt][5], T1v[kt][5]));
        hv[6] = fmaxf(0.f, fmaf(a1.z + q1.z, S1v[kt][6], T1v[kt][6]));
        hv[7] = fmaxf(0.f, fmaf(a1.w + q1.w, S1v[kt][7], T1v[kt][7]));
        uint4 uh;
        uh.x = f2bf(hv[0]) | ((uint)f2bf(hv[1]) << 16);
        uh.y = f2bf(hv[2]) | ((uint)f2bf(hv[3]) << 16);
        uh.z = f2bf(hv[4]) | ((uint)f2bf(hv[5]) << 16);
        uh.w = f2bf(hv[6]) | ((uint)f2bf(hv[7]) << 16);
        hh[pt][t][kt].u = uh;
      }
    }
  }

  float ps[4] = {0.f, 0.f, 0.f, 0.f}, pss[4] = {0.f, 0.f, 0.f, 0.f};
  float mx[2][4], mn[2][4];
#pragma unroll
  for (int pt = 0; pt < 2; ++pt)
#pragma unroll
    for (int ot = 0; ot < 4; ++ot) { mx[pt][ot] = -FLT_MAX; mn[pt][ot] = FLT_MAX; }

#pragma unroll
  for (int ot = 0; ot < 4; ++ot) {
#pragma unroll
    for (int pt = 0; pt < 2; ++pt) {
      f32x4 accA = {0.f, 0.f, 0.f, 0.f};
      accA = __builtin_amdgcn_mfma_f32_16x16x32_bf16(hh[pt][0][0].s, wh[ot][0].s, accA, 0, 0, 0);
      accA = __builtin_amdgcn_mfma_f32_16x16x32_bf16(hh[pt][0][1].s, wh[ot][1].s, accA, 0, 0, 0);
      accA = __builtin_amdgcn_mfma_f32_16x16x32_bf16(hh[pt][0][0].s, wl[ot][0].s, accA, 0, 0, 0);
      accA = __builtin_amdgcn_mfma_f32_16x16x32_bf16(hh[pt][0][1].s, wl[ot][1].s, accA, 0, 0, 0);
      f32x4 accB = {0.f, 0.f, 0.f, 0.f};
      accB = __builtin_amdgcn_mfma_f32_16x16x32_bf16(hh[pt][1][0].s, wh[ot][0].s, accB, 0, 0, 0);
      accB = __builtin_amdgcn_mfma_f32_16x16x32_bf16(hh[pt][1][1].s, wh[ot][1].s, accB, 0, 0, 0);
      accB = __builtin_amdgcn_mfma_f32_16x16x32_bf16(hh[pt][1][0].s, wl[ot][0].s, accB, 0, 0, 0);
      accB = __builtin_amdgcn_mfma_f32_16x16x32_bf16(hh[pt][1][1].s, wl[ot][1].s, accB, 0, 0, 0);
#pragma unroll
      for (int r = 0; r < 4; ++r) {
        float y = accA[r] + b2r[ot];
        mx[pt][ot] = fmaxf(mx[pt][ot], y);
        mn[pt][ot] = fminf(mn[pt][ot], y);
        ps[ot] += y;
        pss[ot] = fmaf(y, y, pss[ot]);
      }
      if (g == 0) {
#pragma unroll
        for (int r = 0; r < 4; ++r) {
          float y = accB[r] + b2r[ot];
          mx[pt][ot] = fmaxf(mx[pt][ot], y);
          mn[pt][ot] = fminf(mn[pt][ot], y);
          ps[ot] += y;
          pss[ot] = fmaf(y, y, pss[ot]);
        }
      }
    }
  }

#pragma unroll
  for (int pt = 0; pt < 2; ++pt) {
#pragma unroll
    for (int ot = 0; ot < 4; ++ot) {
      float v = mx[pt][ot];
      v = fmaxf(v, __shfl_xor(v, 16, 64));
      v = fmaxf(v, __shfl_xor(v, 32, 64));
      mx[pt][ot] = v;
      float u = mn[pt][ot];
      u = fminf(u, __shfl_xor(u, 16, 64));
      u = fminf(u, __shfl_xor(u, 32, 64));
      mn[pt][ot] = u;
    }
    float wmx = mx[pt][0], wmn = mn[pt][0];
    if (g == 1) { wmx = mx[pt][1]; wmn = mn[pt][1]; }
    if (g == 2) { wmx = mx[pt][2]; wmn = mn[pt][2]; }
    if (g == 3) { wmx = mx[pt][3]; wmn = mn[pt][3]; }
    ymax[(size_t)(p0 + pt) * 64 + lane] = wmx;
    ymin[(size_t)(p0 + pt) * 64 + lane] = wmn;
  }

  // BN2 stats: reduce over g (shfl), lane provides o=lane (ot=g), block-reduce
#pragma unroll
  for (int ot = 0; ot < 4; ++ot) {
    float s = ps[ot];
    s += __shfl_xor(s, 16, 64);
    s += __shfl_xor(s, 32, 64);
    ps[ot] = s;
    float q = pss[ot];
    q += __shfl_xor(q, 16, 64);
    q += __shfl_xor(q, 32, 64);
    pss[ot] = q;
  }
  float sv = ps[0], qv = pss[0];
  if (g == 1) { sv = ps[1]; qv = pss[1]; }
  if (g == 2) { sv = ps[2]; qv = pss[2]; }
  if (g == 3) { sv = ps[3]; qv = pss[3]; }
  red2[w * 64 + lane] = sv;
  red2[256 + w * 64 + lane] = qv;
  __syncthreads();
  if (tid < 64) {
    float S = red2[tid] + red2[64 + tid] + red2[128 + tid] + red2[192 + tid];
    float Q = red2[256 + tid] + red2[320 + tid] + red2[384 + tid] + red2[448 + tid];
    atomicAdd(&sums2[tid], S);
    atomicAdd(&sums2[64 + tid], Q);
  }
}

// ---------------- K6a: finalize BN2 ----------------
__global__ void k_fin2(const float* __restrict__ sums2, const float* __restrict__ g2,
                       const float* __restrict__ be2, float* __restrict__ ST2) {
  int o = threadIdx.x;
  const float E = 327680.f;
  float m = sums2[o] / E;
  float var = fmaxf(sums2[64 + o] / E - m * m, 0.f);
  float s = g2[o] / sqrtf(var + EPS_);
  ST2[o] = s;
  ST2[64 + o] = be2[o] - m * s;
}

// ---------------- K6b: epilogue out[b][o][n] ----------------
__global__ __launch_bounds__(256) void k_out(const float* __restrict__ ymax,
                                             const float* __restrict__ ymin,
                                             const float* __restrict__ ST2,
                                             float* __restrict__ out) {
  int t = blockIdx.x * 256 + threadIdx.x;
  int n = t & 4095;
  int o = (t >> 12) & 63;
  int b = t >> 18;
  float s = ST2[o], tt = ST2[64 + o];
  size_t p = ((size_t)b << 12) + n;
  float v = (s >= 0.f) ? ymax[p * 64 + o] : ymin[p * 64 + o];
  out[t] = fmaxf(0.f, fmaf(v, s, tt));
}

extern "C" void kernel_launch(void* const* d_in, const int* in_sizes, int n_in,
                              void* d_out, int out_size, void* d_ws, size_t ws_size,
                              hipStream_t stream) {
  const float* x   = (const float*)d_in[0];
  const float* w1  = (const float*)d_in[1];
  const float* b1  = (const float*)d_in[2];
  const float* g1  = (const float*)d_in[3];
  const float* be1 = (const float*)d_in[4];
  const float* w2  = (const float*)d_in[5];
  const float* b2  = (const float*)d_in[6];
  const float* g2  = (const float*)d_in[7];
  const float* be2 = (const float*)d_in[8];
  float* out = (float*)d_out;
  float* ws = (float*)d_ws;

  float* xx   = ws + OFF_XX;
  float* A    = ws + OFF_A;
  float* Cc   = ws + OFF_CC;
  float* ymax = ws + OFF_YMAX;
  float* ymin = ws + OFF_YMIN;
  float* sums = ws + OFF_SUMS;
  float* ST1  = ws + OFF_ST;
  float* ST2  = ST1 + 128;
  int*   idx  = (int*)(ws + OFF_IDX);
  float* xt   = ws + OFF_XT;
  ushort* Phi = (ushort*)(ws + OFF_PHI);
  ushort* Plo = (ushort*)(ws + OFF_PLO);
  ushort* w2p = (ushort*)(ws + OFF_W2P);

  hipMemsetAsync(sums, 0, 256 * sizeof(float), stream);

  k_prep <<<256,  256, 0, stream>>>(x, w1, xx, xt, Phi, Plo, A, Cc);
  k_knn4 <<<512,  512, 0, stream>>>(Phi, Plo, xx, xt, A, Cc, b1, idx, sums);
  k_fin1 <<<1,    64,  0, stream>>>(sums, b1, g1, be1, w2, ST1, w2p);
  k_l2m2 <<<2048, 256, 0, stream>>>(A, Cc, idx, ST1, w2p, b2, ymax, ymin, sums + 128);
  k_fin2 <<<1,    64,  0, stream>>>(sums + 128, g2, be2, ST2);
  k_out  <<<4096, 256, 0, stream>>>(ymax, ymin, ST2, out);
}